// Round 18
// baseline (629.354 us; speedup 1.0000x reference)
//
#include <hip/hip_runtime.h>
#include <cstdint>

#define C_LEN 4096
#define E_DIM 1024
#define NBATCH 4

typedef __attribute__((ext_vector_type(4))) float f32x4;
typedef __attribute__((ext_vector_type(16))) float f32x16;
typedef __attribute__((ext_vector_type(8))) short bf16x8;
typedef __attribute__((ext_vector_type(4))) unsigned short u16x4;

__device__ __forceinline__ unsigned short f2bf(float f) {
  uint32_t u = __builtin_bit_cast(uint32_t, f);
  return (unsigned short)((u + 0x7fffu + ((u >> 16) & 1u)) >> 16);
}

__device__ __forceinline__ unsigned short f2h(float f) {
  _Float16 h = (_Float16)f;
  return __builtin_bit_cast(unsigned short, h);
}
__device__ __forceinline__ float h2f(unsigned short u) {
  return (float)__builtin_bit_cast(_Float16, u);
}

__device__ __forceinline__ void gl_lds16(const void* g, void* l) {
  __builtin_amdgcn_global_load_lds(
      (const __attribute__((address_space(1))) void*)g,
      (__attribute__((address_space(3))) void*)l, 16, 0, 0);
}

#define BAR() __builtin_amdgcn_s_barrier()
#define VMC(n) asm volatile("s_waitcnt vmcnt(" #n ")" ::: "memory")

// -------- RoPE table: [C][E/2] of float2{cos,sin} (interleaved, 16 MB) --------
__global__ __launch_bounds__(256) void rope_table(float2* __restrict__ csT) {
  int idx = blockIdx.x * 256 + threadIdx.x;  // over C*E/2
  int pos = idx >> 9;
  int i = idx & 511;
  double inv = exp(((double)(-2 * i) / 1024.0) * 9.210340371976184);
  double a = (double)pos * inv;
  double r = a - 6.283185307179586 * rint(a * 0.15915494309189535);
  float rf = (float)r;
  float s, c;
  __sincosf(rf, &s, &c);
  csT[idx] = make_float2(c, s);
}

// -------- fused f32 -> bf16 convert for x, Wq, Wk, Wv --------
__global__ __launch_bounds__(256) void cvt_all(const float* __restrict__ x,
                                               const float* __restrict__ wq,
                                               const float* __restrict__ wk,
                                               const float* __restrict__ wv,
                                               unsigned short* __restrict__ x_bf,
                                               unsigned short* __restrict__ w_bf) {
  int b = blockIdx.x;
  const float* in;
  unsigned short* out;
  long off;
  if (b < 16384) { in = x; out = x_bf; off = (long)b * 1024; }
  else if (b < 17408) { in = wq; out = w_bf; off = (long)(b - 16384) * 1024; }
  else if (b < 18432) { in = wk; out = w_bf + (1l << 20); off = (long)(b - 17408) * 1024; }
  else { in = wv; out = w_bf + (2l << 20); off = (long)(b - 18432) * 1024; }
  long i = off + threadIdx.x * 4;
  f32x4 v = *(const f32x4*)(in + i);
  u16x4 o = {f2bf(v.x), f2bf(v.y), f2bf(v.z), f2bf(v.w)};
  *(u16x4*)(out + i) = o;
}

// ======== 256x256 8-phase GEMM, BK=64 — r16 skeleton + 32x32x16 MFMA ========
// 512 threads = 8 waves (2M x 4N). LDS 128 KiB [buf(2)][A/B][half][128][64].
// Identical phase/staging/vmcnt structure to r16 (best measured); only the
// fragment enumeration + MFMA shape change: wave tile 128x64 as 4x2 frags of
// 32x32, K-slab 16 -> 8 MFMA/phase (was 16), same 12 ds_read_b128/phase, same
// register budget. Swizzle g ^= row&7 spreads 32-row frags over all 8 granule
// groups: 8 lanes/bank x 4B = the 1024B/wave floor -> conflict-free-equiv.
// A frag: row=lane&31, k=(lane>>5)*8+e. C/D: col=lane&31,
// row=(r&3)+8*(r>>2)+4*(lane>>5)  [r9 refcheck-verified on this op].
// MODE 0: fused QKV projection (N=3072=[Q|K|V]); RoPE on Q/K, transpose V.
// MODE 2: *1/32 + mask, f16 scores packed into first 8KB of each f32 row slot.
// MODE 3: plain f32 out (PV).
template <int MODE>
__global__ __launch_bounds__(512, 1) void gemm8(
    const unsigned short* __restrict__ A, const unsigned short* __restrict__ Bm,
    long sAb, long sBb, long sOb, int nr, int nc, int K, int N,
    unsigned short* __restrict__ oQ, unsigned short* __restrict__ oK,
    unsigned short* __restrict__ oVt, float* __restrict__ oF,
    const float2* __restrict__ csT, const float* __restrict__ mask) {
  __shared__ unsigned short lds[2][2][2][128 * 64];  // 128 KiB
  const int tid = threadIdx.x;
  const int lane = tid & 63;
  const int wid = tid >> 6;
  const int wm = wid >> 2, wn = wid & 3;  // 2M x 4N
  const int l31 = lane & 31, khalf = lane >> 5;

  // XCD chunk (nwg%8==0) + 4x4 supertile decode (nr%4==0, nc%4==0)
  const int nwg = gridDim.x;
  const int lid = blockIdx.x;
  const int s = (lid & 7) * (nwg >> 3) + (lid >> 3);
  int bz, rt, ct;
  if (MODE == 2) {
    // batch innermost: 4 consecutive same-XCD blocks share (rt,ct) mask tile
    bz = s & 3;
    const int s4 = s >> 2;
    const int scc = nc >> 2;
    const int sid = s4 >> 4, inner = s4 & 15;
    const int srt = sid / scc, sct = sid - srt * scc;
    rt = srt * 4 + (inner >> 2);
    ct = sct * 4 + (inner & 3);
  } else {
    const int scc = nc >> 2;
    const int per_b_st = (nr >> 2) * scc;
    const int sid = s >> 4, inner = s & 15;
    bz = sid / per_b_st;
    const int r2 = sid - bz * per_b_st;
    const int srt = r2 / scc, sct = r2 - srt * scc;
    rt = srt * 4 + (inner >> 2);
    ct = sct * 4 + (inner & 3);
  }

  const unsigned short* Ag = A + sAb * bz + (long)rt * 256 * K;
  const unsigned short* Bg = Bm + sBb * bz + (long)ct * 256 * K;

  // stage one half-tile (128x64) = 2 gl_lds/thread; LDS linear, src col
  // granule inverse-swizzled by the read involution (g ^= row&7).
  auto stA = [&](int buf, int half, int t) {
#pragma unroll
    for (int q = 0; q < 2; ++q) {
      int G = q * 512 + tid;
      int r = G >> 3, g = G & 7;
      gl_lds16(Ag + (long)(half * 128 + r) * K + t * 64 + ((g ^ (r & 7)) << 3),
               &lds[buf][0][half][G * 8]);
    }
  };
  auto stB = [&](int buf, int half, int t) {
#pragma unroll
    for (int q = 0; q < 2; ++q) {
      int G = q * 512 + tid;
      int r = G >> 3, g = G & 7;
      gl_lds16(Bg + (long)(half * 128 + r) * K + t * 64 + ((g ^ (r & 7)) << 3),
               &lds[buf][1][half][G * 8]);
    }
  };

  f32x16 acc[4][2];  // [mf_global 0..3][nf 0..1], 32x32 frags, 128 f32 total
#pragma unroll
  for (int mf = 0; mf < 4; ++mf)
#pragma unroll
    for (int nf = 0; nf < 2; ++nf)
#pragma unroll
      for (int r = 0; r < 16; ++r) acc[mf][nf][r] = 0.f;

  bf16x8 aF[8], aF2[8], bF0[4], bF1[4];
  // A mh-half: 2 mf-frags x 4 k-slabs = 8 reads (d[mf*4+ks])
  auto rdA = [&](int buf, int mh, bf16x8* d) {
#pragma unroll
    for (int mf = 0; mf < 2; ++mf) {
      int row = mh * 64 + mf * 32 + l31;
#pragma unroll
      for (int ks = 0; ks < 4; ++ks) {
        int g = ks * 2 + khalf;
        d[mf * 4 + ks] = *(const bf16x8*)&lds[buf][0][wm]
            [row * 64 + ((g ^ (row & 7)) << 3)];
      }
    }
  };
  // B nh-frag: 1 frag x 4 k-slabs = 4 reads (d[ks])
  auto rdB = [&](int buf, int nh, bf16x8* d) {
    int row = (wn & 1) * 64 + nh * 32 + l31;
#pragma unroll
    for (int ks = 0; ks < 4; ++ks) {
      int g = ks * 2 + khalf;
      d[ks] = *(const bf16x8*)&lds[buf][1][wn >> 1]
          [row * 64 + ((g ^ (row & 7)) << 3)];
    }
  };
  auto mm = [&](bf16x8* af, bf16x8* bf, int mh, int nh) {
    __builtin_amdgcn_s_setprio(1);
#pragma unroll
    for (int ks = 0; ks < 4; ++ks)
#pragma unroll
      for (int mf = 0; mf < 2; ++mf)
        acc[mh * 2 + mf][nh] = __builtin_amdgcn_mfma_f32_32x32x16_bf16(
            af[mf * 4 + ks], bf[ks], acc[mh * 2 + mf][nh], 0, 0, 0);
    __builtin_amdgcn_s_setprio(0);
  };

  const int NIT = K >> 7;  // 2 K-tiles (BK=64) per iteration
  stA(0, 0, 0); stA(0, 1, 0); stB(0, 0, 0); stB(0, 1, 0);
  stA(1, 0, 1); stA(1, 1, 1); stB(1, 0, 1); stB(1, 1, 1);
  VMC(8);
  BAR();

  for (int it = 0; it < NIT; ++it) {
    const int t1 = 2 * it + 1, t2 = 2 * it + 2, t3 = 2 * it + 3;
    const bool more = (it + 1 < NIT);
    // ---- ph1: t0 (mh0,nh0); tail-read bF1 for ph2 ----
    rdA(0, 0, aF); rdB(0, 0, bF0);
    if (it > 0) stA(1, 0, t1);
    BAR();
    mm(aF, bF0, 0, 0);
    rdB(0, 1, bF1);        // interleaves with MFMA drain (bF1 unused by ph1)
    BAR();
    // ---- ph2: t0 (mh0,nh1); tail-read aF2 for ph3 ----
    if (it > 0) stA(1, 1, t1);
    BAR();
    mm(aF, bF1, 0, 1);
    rdA(0, 1, aF2);        // interleaves with MFMA drain (aF2 distinct)
    BAR();
    // ---- ph3: t0 (mh1,nh1) ---- buf0-B sealed at ph2 end
    if (more) stB(0, 0, t2);
    BAR();
    mm(aF2, bF1, 1, 1);
    BAR();
    // ---- ph4: t0 (mh1,nh0) ---- vmcnt: tile t1 fully landed for ph5
    if (more) stB(0, 1, t2);
    BAR();
    mm(aF2, bF0, 1, 0);
    if (more) { VMC(4); } else { VMC(0); }
    BAR();
    // ---- ph5: t1 (mh0,nh0); tail-read bF1 ----
    rdA(1, 0, aF); rdB(1, 0, bF0);
    if (more) stA(0, 0, t2);
    BAR();
    mm(aF, bF0, 0, 0);
    rdB(1, 1, bF1);
    BAR();
    // ---- ph6: t1 (mh0,nh1); tail-read aF2 ----
    if (more) stA(0, 1, t2);
    BAR();
    mm(aF, bF1, 0, 1);
    rdA(1, 1, aF2);
    BAR();
    // ---- ph7: t1 (mh1,nh1) ---- buf1-B sealed at ph6 end
    if (more) stB(1, 0, t3);
    BAR();
    mm(aF2, bF1, 1, 1);
    BAR();
    // ---- ph8: t1 (mh1,nh0) ---- vmcnt: tile t2 fully landed for next ph1
    if (more) stB(1, 1, t3);
    BAR();
    mm(aF2, bF0, 1, 0);
    if (more) { VMC(4); BAR(); }
  }

  const int row0 = rt * 256 + wm * 128;
  const int col0 = ct * 256 + wn * 64;
#pragma unroll
  for (int mf = 0; mf < 4; ++mf) {
#pragma unroll
    for (int nf = 0; nf < 2; ++nf) {
#pragma unroll
      for (int r = 0; r < 16; ++r) {
        float v = acc[mf][nf][r];
        // 32x32 C/D: col=lane&31, row=(r&3)+8*(r>>2)+4*(lane>>5)
        int row = row0 + mf * 32 + ((r & 3) + 8 * (r >> 2) + 4 * khalf);
        int col = col0 + nf * 32 + l31;
        if (MODE == 0) {
          float pp = __shfl_xor(v, 1);  // RoPE pair partner (col^1 -> lane^1)
          int sel = col >> 10;          // 0=Q 1=K 2=V (uniform per 32-col frag)
          int lcol = col & 1023;
          if (sel < 2) {
            int pos = row & (C_LEN - 1);
            float2 cs = csT[pos * (E_DIM / 2) + (lcol >> 1)];
            float rv = v * cs.x + ((lcol & 1) ? pp * cs.y : -pp * cs.y);
            unsigned short* o = sel ? oK : oQ;
            o[(long)row * E_DIM + lcol] = f2bf(rv);
          } else {
            int b = row >> 12;
            int cc = row & (C_LEN - 1);
            oVt[(long)b * E_DIM * C_LEN + (long)lcol * C_LEN + cc] = f2bf(v);
          }
        } else if (MODE == 2) {
          float sc = v * 0.03125f + mask[(long)row * C_LEN + col];
          // f16 score packed into the first 8 KB of this row's f32 slot
          unsigned short* rowp =
              (unsigned short*)(oF + sOb * bz + (long)row * C_LEN);
          rowp[col] = f2h(sc);
        } else {
          oF[sOb * bz + (long)row * N + col] = v;
        }
      }
    }
  }
}

// -------- row softmax: read f16 scores (own row's first 8 KB), write f32
// weights in place + bf16 P copy. Row-local: no cross-row hazard. --------
__global__ __launch_bounds__(256) void softmax_rows(float* __restrict__ w,
                                                    unsigned short* __restrict__ pb) {
  long row = blockIdx.x;
  float* p = w + row * C_LEN;
  const unsigned short* ph = (const unsigned short*)p;  // f16 scores
  unsigned short* pbp = pb + row * C_LEN;
  int t = threadIdx.x;
  int wid = t >> 6;
  f32x4 v[4];
  float mx = -3.4e38f;
#pragma unroll
  for (int j = 0; j < 4; ++j) {
    u16x4 hb = *(const u16x4*)(ph + j * 1024 + t * 4);
    v[j].x = h2f(hb.x);
    v[j].y = h2f(hb.y);
    v[j].z = h2f(hb.z);
    v[j].w = h2f(hb.w);
    mx = fmaxf(mx, fmaxf(fmaxf(v[j].x, v[j].y), fmaxf(v[j].z, v[j].w)));
  }
#pragma unroll
  for (int o = 1; o < 64; o <<= 1) mx = fmaxf(mx, __shfl_xor(mx, o));
  __shared__ float redm[4];
  if ((t & 63) == 0) redm[wid] = mx;
  __syncthreads();
  mx = fmaxf(fmaxf(redm[0], redm[1]), fmaxf(redm[2], redm[3]));
  float sum = 0.f;
#pragma unroll
  for (int j = 0; j < 4; ++j) {
    v[j].x = __expf(v[j].x - mx);
    v[j].y = __expf(v[j].y - mx);
    v[j].z = __expf(v[j].z - mx);
    v[j].w = __expf(v[j].w - mx);
    sum += v[j].x + v[j].y + v[j].z + v[j].w;
  }
#pragma unroll
  for (int o = 1; o < 64; o <<= 1) sum += __shfl_xor(sum, o);
  __shared__ float reds[4];
  if ((t & 63) == 0) reds[wid] = sum;
  __syncthreads();
  sum = reds[0] + reds[1] + reds[2] + reds[3];
  float inv = 1.0f / sum;
  __syncthreads();  // all reads of this row's f16 data complete before stores
#pragma unroll
  for (int j = 0; j < 4; ++j) {
    v[j].x *= inv;
    v[j].y *= inv;
    v[j].z *= inv;
    v[j].w *= inv;
    __builtin_nontemporal_store(v[j], (f32x4*)(p + j * 1024 + t * 4));
    u16x4 o16 = {f2bf(v[j].x), f2bf(v[j].y), f2bf(v[j].z), f2bf(v[j].w)};
    *(u16x4*)(pbp + j * 1024 + t * 4) = o16;
  }
}

extern "C" void kernel_launch(void* const* d_in, const int* in_sizes, int n_in,
                              void* d_out, int out_size, void* d_ws, size_t ws_size,
                              hipStream_t stream) {
  const float* x = (const float*)d_in[0];
  const float* mask = (const float*)d_in[1];
  const float* Wq = (const float*)d_in[2];
  const float* Wk = (const float*)d_in[3];
  const float* Wv = (const float*)d_in[4];
  float* out = (float*)d_out;                           // [B][C][E]
  float* weights = out + (long)NBATCH * C_LEN * E_DIM;  // [B][C][C]

  char* ws = (char*)d_ws;
  const bool big = ws_size >= (160ull << 20);
  float2* csT = (float2*)(ws);                               // 16 MB (dead after proj)
  unsigned short* x_bf = (unsigned short*)(ws + (16l << 20));
  unsigned short* W_bf = (unsigned short*)(ws + (48l << 20));  // [3072][1024] = Q|K|V
  unsigned short* Q_bf = (unsigned short*)(ws + (54l << 20));
  unsigned short* K_bf = (unsigned short*)(ws + (86l << 20));
  unsigned short* Vt = (unsigned short*)(ws + (big ? (128l << 20) : (118l << 20)));
  unsigned short* P_bf = (unsigned short*)(ws);  // reuses csT region after proj

  dim3 blk(256);
  dim3 blk512(512);

  rope_table<<<dim3((C_LEN * (E_DIM / 2)) / 256), blk, 0, stream>>>(csT);
  cvt_all<<<dim3(19456), blk, 0, stream>>>(x, Wq, Wk, Wv, x_bf, W_bf);

  // fused QKV projection: 64 rt x 12 ct = 768 blocks
  gemm8<0><<<dim3(768), blk512, 0, stream>>>(
      x_bf, W_bf, 0, 0, 0, 64, 12, E_DIM, 3 * E_DIM,
      Q_bf, K_bf, Vt, nullptr, csT, nullptr);

  // scores = QK^T/32 + mask -> f16 packed into weights rows; 1024 blocks
  gemm8<2><<<dim3(1024), blk512, 0, stream>>>(
      Q_bf, K_bf, (long)C_LEN * E_DIM, (long)C_LEN * E_DIM, (long)C_LEN * C_LEN,
      16, 16, E_DIM, C_LEN, nullptr, nullptr, nullptr, weights, nullptr, mask);

  if (big) {
    softmax_rows<<<dim3(NBATCH * C_LEN), blk, 0, stream>>>(weights, P_bf);
    // out = P @ V: 16 rt x 4 ct x 4 bz = 256 blocks
    gemm8<3><<<dim3(256), blk512, 0, stream>>>(
        P_bf, Vt, (long)C_LEN * C_LEN, (long)E_DIM * C_LEN, (long)C_LEN * E_DIM,
        16, 4, C_LEN, E_DIM, nullptr, nullptr, nullptr, out, nullptr, nullptr);
  } else {
    for (int h = 0; h < 2; ++h) {
      float* wgt = weights + (long)h * 2 * C_LEN * C_LEN;
      softmax_rows<<<dim3(2 * C_LEN), blk, 0, stream>>>(wgt, P_bf);
      gemm8<3><<<dim3(128), blk512, 0, stream>>>(
          P_bf, Vt + (long)h * 2 * E_DIM * C_LEN, (long)C_LEN * C_LEN, (long)E_DIM * C_LEN,
          (long)C_LEN * E_DIM, 16, 4, C_LEN, E_DIM,
          nullptr, nullptr, nullptr, out + (long)h * 2 * C_LEN * E_DIM,
          nullptr, nullptr);
    }
  }
}

// Round 19
// 581.853 us; speedup vs baseline: 1.0816x; 1.0816x over previous
//
#include <hip/hip_runtime.h>
#include <cstdint>

#define C_LEN 4096
#define E_DIM 1024
#define NBATCH 4

typedef __attribute__((ext_vector_type(4))) float f32x4;
typedef __attribute__((ext_vector_type(8))) short bf16x8;
typedef __attribute__((ext_vector_type(4))) unsigned short u16x4;

__device__ __forceinline__ unsigned short f2bf(float f) {
  uint32_t u = __builtin_bit_cast(uint32_t, f);
  return (unsigned short)((u + 0x7fffu + ((u >> 16) & 1u)) >> 16);
}

__device__ __forceinline__ unsigned short f2h(float f) {
  _Float16 h = (_Float16)f;
  return __builtin_bit_cast(unsigned short, h);
}
__device__ __forceinline__ float h2f(unsigned short u) {
  return (float)__builtin_bit_cast(_Float16, u);
}

__device__ __forceinline__ void gl_lds16(const void* g, void* l) {
  __builtin_amdgcn_global_load_lds(
      (const __attribute__((address_space(1))) void*)g,
      (__attribute__((address_space(3))) void*)l, 16, 0, 0);
}

#define BAR() __builtin_amdgcn_s_barrier()
#define VMC(n) asm volatile("s_waitcnt vmcnt(" #n ")" ::: "memory")

// -------- RoPE cos/sin table: [C][E/2] f32 each --------
__global__ __launch_bounds__(256) void rope_table(float* __restrict__ cosT,
                                                  float* __restrict__ sinT) {
  int idx = blockIdx.x * 256 + threadIdx.x;  // over C*E/2
  int pos = idx >> 9;
  int i = idx & 511;
  double inv = exp(((double)(-2 * i) / 1024.0) * 9.210340371976184);
  double a = (double)pos * inv;
  double r = a - 6.283185307179586 * rint(a * 0.15915494309189535);
  float rf = (float)r;
  float s, c;
  __sincosf(rf, &s, &c);
  cosT[idx] = c;
  sinT[idx] = s;
}

// -------- fused f32 -> bf16 convert for x, Wq, Wk, Wv --------
__global__ __launch_bounds__(256) void cvt_all(const float* __restrict__ x,
                                               const float* __restrict__ wq,
                                               const float* __restrict__ wk,
                                               const float* __restrict__ wv,
                                               unsigned short* __restrict__ x_bf,
                                               unsigned short* __restrict__ w_bf) {
  int b = blockIdx.x;
  const float* in;
  unsigned short* out;
  long off;
  if (b < 16384) { in = x; out = x_bf; off = (long)b * 1024; }
  else if (b < 17408) { in = wq; out = w_bf; off = (long)(b - 16384) * 1024; }
  else if (b < 18432) { in = wk; out = w_bf + (1l << 20); off = (long)(b - 17408) * 1024; }
  else { in = wv; out = w_bf + (2l << 20); off = (long)(b - 18432) * 1024; }
  long i = off + threadIdx.x * 4;
  f32x4 v = *(const f32x4*)(in + i);
  u16x4 o = {f2bf(v.x), f2bf(v.y), f2bf(v.z), f2bf(v.w)};
  *(u16x4*)(out + i) = o;
}

// ======== 256x256 8-phase GEMM, BK=64 — r16 structure (best measured) ========
// 512 threads = 8 waves (2M x 4N). LDS 128 KiB [buf(2)][A/B][half][128][64].
// Top-of-phase ds_reads overlap the barrier wait; tail-reads (bF1/aF2) overlap
// the MFMA drain; compiler emits fine-grained lgkmcnt (no manual pins). Stage
// slots each land after their buffer-half's seal barrier; vmcnt(4) at ph4/ph8
// only. Swizzle: granule ^= row&7 (0 conflicts with 16-row frags),
// inverse-permuted global src + linear gl_lds dest. XCD chunk + 4x4 supertile;
// MODE 2 batch-innermost (mask tile L2 shared).
// MODE 0: fused QKV projection (N=3072=[Q|K|V]); RoPE on Q/K, transpose V.
// MODE 2: *1/32 + mask, f16 scores packed into first 8KB of each f32 row slot.
// MODE 3: plain f32 out (PV).
template <int MODE>
__global__ __launch_bounds__(512, 1) void gemm8(
    const unsigned short* __restrict__ A, const unsigned short* __restrict__ Bm,
    long sAb, long sBb, long sOb, int nr, int nc, int K, int N,
    unsigned short* __restrict__ oQ, unsigned short* __restrict__ oK,
    unsigned short* __restrict__ oVt, float* __restrict__ oF,
    const float* __restrict__ cosT, const float* __restrict__ sinT,
    const float* __restrict__ mask) {
  __shared__ unsigned short lds[2][2][2][128 * 64];  // 128 KiB
  const int tid = threadIdx.x;
  const int lane = tid & 63;
  const int wid = tid >> 6;
  const int wm = wid >> 2, wn = wid & 3;  // 2M x 4N
  const int kgrp = lane >> 4, r16 = lane & 15;

  // XCD chunk (nwg%8==0) + 4x4 supertile decode (nr%4==0, nc%4==0)
  const int nwg = gridDim.x;
  const int lid = blockIdx.x;
  const int s = (lid & 7) * (nwg >> 3) + (lid >> 3);
  int bz, rt, ct;
  if (MODE == 2) {
    // batch innermost: 4 consecutive same-XCD blocks share (rt,ct) mask tile
    bz = s & 3;
    const int s4 = s >> 2;
    const int scc = nc >> 2;
    const int sid = s4 >> 4, inner = s4 & 15;
    const int srt = sid / scc, sct = sid - srt * scc;
    rt = srt * 4 + (inner >> 2);
    ct = sct * 4 + (inner & 3);
  } else {
    const int scc = nc >> 2;
    const int per_b_st = (nr >> 2) * scc;
    const int sid = s >> 4, inner = s & 15;
    bz = sid / per_b_st;
    const int r2 = sid - bz * per_b_st;
    const int srt = r2 / scc, sct = r2 - srt * scc;
    rt = srt * 4 + (inner >> 2);
    ct = sct * 4 + (inner & 3);
  }

  const unsigned short* Ag = A + sAb * bz + (long)rt * 256 * K;
  const unsigned short* Bg = Bm + sBb * bz + (long)ct * 256 * K;

  // stage one half-tile (128x64) = 2 gl_lds/thread; LDS linear, src col
  // granule inverse-swizzled by the read involution (g ^= row&7).
  auto stA = [&](int buf, int half, int t) {
#pragma unroll
    for (int q = 0; q < 2; ++q) {
      int G = q * 512 + tid;
      int r = G >> 3, g = G & 7;
      gl_lds16(Ag + (long)(half * 128 + r) * K + t * 64 + ((g ^ (r & 7)) << 3),
               &lds[buf][0][half][G * 8]);
    }
  };
  auto stB = [&](int buf, int half, int t) {
#pragma unroll
    for (int q = 0; q < 2; ++q) {
      int G = q * 512 + tid;
      int r = G >> 3, g = G & 7;
      gl_lds16(Bg + (long)(half * 128 + r) * K + t * 64 + ((g ^ (r & 7)) << 3),
               &lds[buf][1][half][G * 8]);
    }
  };

  f32x4 acc[8][4];
#pragma unroll
  for (int m = 0; m < 8; ++m)
#pragma unroll
    for (int n = 0; n < 4; ++n) acc[m][n] = {0.f, 0.f, 0.f, 0.f};

  bf16x8 aF[8], aF2[8], bF0[4], bF1[4];
  auto rdA = [&](int buf, int mh, bf16x8* d) {
#pragma unroll
    for (int m = 0; m < 4; ++m) {
      int row = mh * 64 + m * 16 + r16;
#pragma unroll
      for (int ks = 0; ks < 2; ++ks)
        d[m * 2 + ks] = *(const bf16x8*)&lds[buf][0][wm]
            [row * 64 + ((((ks << 2) + kgrp) ^ (row & 7)) << 3)];
    }
  };
  auto rdB = [&](int buf, int nh, bf16x8* d) {
#pragma unroll
    for (int n = 0; n < 2; ++n) {
      int row = (wn & 1) * 64 + nh * 32 + n * 16 + r16;
#pragma unroll
      for (int ks = 0; ks < 2; ++ks)
        d[n * 2 + ks] = *(const bf16x8*)&lds[buf][1][wn >> 1]
            [row * 64 + ((((ks << 2) + kgrp) ^ (row & 7)) << 3)];
    }
  };
  auto mm = [&](bf16x8* af, bf16x8* bf, int mh, int nh) {
    __builtin_amdgcn_s_setprio(1);
#pragma unroll
    for (int ks = 0; ks < 2; ++ks)
#pragma unroll
      for (int m = 0; m < 4; ++m)
#pragma unroll
        for (int n = 0; n < 2; ++n)
          acc[mh * 4 + m][nh * 2 + n] = __builtin_amdgcn_mfma_f32_16x16x32_bf16(
              af[m * 2 + ks], bf[n * 2 + ks], acc[mh * 4 + m][nh * 2 + n], 0, 0, 0);
    __builtin_amdgcn_s_setprio(0);
  };

  const int NIT = K >> 7;  // 2 K-tiles (BK=64) per iteration
  stA(0, 0, 0); stA(0, 1, 0); stB(0, 0, 0); stB(0, 1, 0);
  stA(1, 0, 1); stA(1, 1, 1); stB(1, 0, 1); stB(1, 1, 1);
  VMC(8);
  BAR();

  for (int it = 0; it < NIT; ++it) {
    const int t1 = 2 * it + 1, t2 = 2 * it + 2, t3 = 2 * it + 3;
    const bool more = (it + 1 < NIT);
    // ---- ph1: t0 (mh0,nh0); tail-read bF1 for ph2 ----
    rdA(0, 0, aF); rdB(0, 0, bF0);
    if (it > 0) stA(1, 0, t1);
    BAR();
    mm(aF, bF0, 0, 0);
    rdB(0, 1, bF1);        // interleaves with MFMA drain (bF1 unused by ph1)
    BAR();
    // ---- ph2: t0 (mh0,nh1); tail-read aF2 for ph3 ----
    if (it > 0) stA(1, 1, t1);
    BAR();
    mm(aF, bF1, 0, 1);
    rdA(0, 1, aF2);        // interleaves with MFMA drain (aF2 distinct)
    BAR();
    // ---- ph3: t0 (mh1,nh1) ---- buf0-B sealed at ph2 end
    if (more) stB(0, 0, t2);
    BAR();
    mm(aF2, bF1, 1, 1);
    BAR();
    // ---- ph4: t0 (mh1,nh0) ---- vmcnt: tile t1 fully landed for ph5
    if (more) stB(0, 1, t2);
    BAR();
    mm(aF2, bF0, 1, 0);
    if (more) { VMC(4); } else { VMC(0); }
    BAR();
    // ---- ph5: t1 (mh0,nh0); tail-read bF1 ----
    rdA(1, 0, aF); rdB(1, 0, bF0);
    if (more) stA(0, 0, t2);
    BAR();
    mm(aF, bF0, 0, 0);
    rdB(1, 1, bF1);
    BAR();
    // ---- ph6: t1 (mh0,nh1); tail-read aF2 ----
    if (more) stA(0, 1, t2);
    BAR();
    mm(aF, bF1, 0, 1);
    rdA(1, 1, aF2);
    BAR();
    // ---- ph7: t1 (mh1,nh1) ---- buf1-B sealed at ph6 end
    if (more) stB(1, 0, t3);
    BAR();
    mm(aF2, bF1, 1, 1);
    BAR();
    // ---- ph8: t1 (mh1,nh0) ---- vmcnt: tile t2 fully landed for next ph1
    if (more) stB(1, 1, t3);
    BAR();
    mm(aF2, bF0, 1, 0);
    if (more) { VMC(4); BAR(); }
  }

  const int row0 = rt * 256 + wm * 128;
  const int col0 = ct * 256 + wn * 64;
#pragma unroll
  for (int m = 0; m < 8; ++m) {
#pragma unroll
    for (int n = 0; n < 4; ++n) {
#pragma unroll
      for (int r = 0; r < 4; ++r) {
        float v = acc[m][n][r];
        int row = row0 + m * 16 + kgrp * 4 + r;  // C/D: col=lane&15, row=(lane>>4)*4+r
        int col = col0 + n * 16 + r16;
        if (MODE == 0) {
          float pp = __shfl_xor(v, 1);  // RoPE pair partner (col^1, same row/reg)
          int sel = col >> 10;          // 0=Q 1=K 2=V (uniform per 64-col wave slice)
          int lcol = col & 1023;
          if (sel < 2) {
            int pos = row & (C_LEN - 1);
            int i2 = lcol >> 1;
            float c = cosT[pos * (E_DIM / 2) + i2];
            float sn = sinT[pos * (E_DIM / 2) + i2];
            float rv = v * c + ((lcol & 1) ? pp * sn : -pp * sn);
            unsigned short* o = sel ? oK : oQ;
            o[(long)row * E_DIM + lcol] = f2bf(rv);
          } else {
            int b = row >> 12;
            int cc = row & (C_LEN - 1);
            oVt[(long)b * E_DIM * C_LEN + (long)lcol * C_LEN + cc] = f2bf(v);
          }
        } else if (MODE == 2) {
          float sc = v * 0.03125f + mask[(long)row * C_LEN + col];
          // f16 score packed into the first 8 KB of this row's f32 slot
          unsigned short* rowp =
              (unsigned short*)(oF + sOb * bz + (long)row * C_LEN);
          rowp[col] = f2h(sc);
        } else {
          oF[sOb * bz + (long)row * N + col] = v;
        }
      }
    }
  }
}

// -------- row softmax: read f16 scores (own row's first 8 KB), write f32
// weights in place + bf16 P copy. Row-local: no cross-row hazard. --------
__global__ __launch_bounds__(256) void softmax_rows(float* __restrict__ w,
                                                    unsigned short* __restrict__ pb) {
  long row = blockIdx.x;
  float* p = w + row * C_LEN;
  const unsigned short* ph = (const unsigned short*)p;  // f16 scores
  unsigned short* pbp = pb + row * C_LEN;
  int t = threadIdx.x;
  int wid = t >> 6;
  f32x4 v[4];
  float mx = -3.4e38f;
#pragma unroll
  for (int j = 0; j < 4; ++j) {
    u16x4 hb = *(const u16x4*)(ph + j * 1024 + t * 4);
    v[j].x = h2f(hb.x);
    v[j].y = h2f(hb.y);
    v[j].z = h2f(hb.z);
    v[j].w = h2f(hb.w);
    mx = fmaxf(mx, fmaxf(fmaxf(v[j].x, v[j].y), fmaxf(v[j].z, v[j].w)));
  }
#pragma unroll
  for (int o = 1; o < 64; o <<= 1) mx = fmaxf(mx, __shfl_xor(mx, o));
  __shared__ float redm[4];
  if ((t & 63) == 0) redm[wid] = mx;
  __syncthreads();
  mx = fmaxf(fmaxf(redm[0], redm[1]), fmaxf(redm[2], redm[3]));
  float sum = 0.f;
#pragma unroll
  for (int j = 0; j < 4; ++j) {
    v[j].x = __expf(v[j].x - mx);
    v[j].y = __expf(v[j].y - mx);
    v[j].z = __expf(v[j].z - mx);
    v[j].w = __expf(v[j].w - mx);
    sum += v[j].x + v[j].y + v[j].z + v[j].w;
  }
#pragma unroll
  for (int o = 1; o < 64; o <<= 1) sum += __shfl_xor(sum, o);
  __shared__ float reds[4];
  if ((t & 63) == 0) reds[wid] = sum;
  __syncthreads();
  sum = reds[0] + reds[1] + reds[2] + reds[3];
  float inv = 1.0f / sum;
  __syncthreads();  // all reads of this row's f16 data complete before stores
#pragma unroll
  for (int j = 0; j < 4; ++j) {
    v[j].x *= inv;
    v[j].y *= inv;
    v[j].z *= inv;
    v[j].w *= inv;
    __builtin_nontemporal_store(v[j], (f32x4*)(p + j * 1024 + t * 4));
    u16x4 o16 = {f2bf(v[j].x), f2bf(v[j].y), f2bf(v[j].z), f2bf(v[j].w)};
    *(u16x4*)(pbp + j * 1024 + t * 4) = o16;
  }
}

extern "C" void kernel_launch(void* const* d_in, const int* in_sizes, int n_in,
                              void* d_out, int out_size, void* d_ws, size_t ws_size,
                              hipStream_t stream) {
  const float* x = (const float*)d_in[0];
  const float* mask = (const float*)d_in[1];
  const float* Wq = (const float*)d_in[2];
  const float* Wk = (const float*)d_in[3];
  const float* Wv = (const float*)d_in[4];
  float* out = (float*)d_out;                           // [B][C][E]
  float* weights = out + (long)NBATCH * C_LEN * E_DIM;  // [B][C][C]

  char* ws = (char*)d_ws;
  const bool big = ws_size >= (160ull << 20);
  float* cosT = (float*)(ws);
  float* sinT = (float*)(ws + (8l << 20));
  unsigned short* x_bf = (unsigned short*)(ws + (16l << 20));
  unsigned short* W_bf = (unsigned short*)(ws + (48l << 20));  // [3072][1024] = Q|K|V
  unsigned short* Q_bf = (unsigned short*)(ws + (54l << 20));
  unsigned short* K_bf = (unsigned short*)(ws + (86l << 20));
  unsigned short* Vt = (unsigned short*)(ws + (big ? (128l << 20) : (118l << 20)));
  unsigned short* P_bf = (unsigned short*)(ws);

  dim3 blk(256);
  dim3 blk512(512);

  rope_table<<<dim3((C_LEN * (E_DIM / 2)) / 256), blk, 0, stream>>>(cosT, sinT);
  cvt_all<<<dim3(19456), blk, 0, stream>>>(x, Wq, Wk, Wv, x_bf, W_bf);

  // fused QKV projection: 64 rt x 12 ct = 768 blocks
  gemm8<0><<<dim3(768), blk512, 0, stream>>>(
      x_bf, W_bf, 0, 0, 0, 64, 12, E_DIM, 3 * E_DIM,
      Q_bf, K_bf, Vt, nullptr, cosT, sinT, nullptr);

  // scores = QK^T/32 + mask -> f16 packed into weights rows; 1024 blocks
  gemm8<2><<<dim3(1024), blk512, 0, stream>>>(
      Q_bf, K_bf, (long)C_LEN * E_DIM, (long)C_LEN * E_DIM, (long)C_LEN * C_LEN,
      16, 16, E_DIM, C_LEN, nullptr, nullptr, nullptr, weights, nullptr, nullptr, mask);

  if (big) {
    softmax_rows<<<dim3(NBATCH * C_LEN), blk, 0, stream>>>(weights, P_bf);
    // out = P @ V: 16 rt x 4 ct x 4 bz = 256 blocks
    gemm8<3><<<dim3(256), blk512, 0, stream>>>(
        P_bf, Vt, (long)C_LEN * C_LEN, (long)E_DIM * C_LEN, (long)C_LEN * E_DIM,
        16, 4, C_LEN, E_DIM, nullptr, nullptr, nullptr, out, nullptr, nullptr, nullptr);
  } else {
    for (int h = 0; h < 2; ++h) {
      float* wgt = weights + (long)h * 2 * C_LEN * C_LEN;
      softmax_rows<<<dim3(2 * C_LEN), blk, 0, stream>>>(wgt, P_bf);
      gemm8<3><<<dim3(128), blk512, 0, stream>>>(
          P_bf, Vt + (long)h * 2 * E_DIM * C_LEN, (long)C_LEN * C_LEN, (long)E_DIM * C_LEN,
          (long)C_LEN * E_DIM, 16, 4, C_LEN, E_DIM,
          nullptr, nullptr, nullptr, out + (long)h * 2 * C_LEN * E_DIM,
          nullptr, nullptr, nullptr);
    }
  }
}

// Round 20
// 568.763 us; speedup vs baseline: 1.1065x; 1.0230x over previous
//
#include <hip/hip_runtime.h>
#include <cstdint>

#define C_LEN 4096
#define E_DIM 1024
#define NBATCH 4

typedef __attribute__((ext_vector_type(4))) float f32x4;
typedef __attribute__((ext_vector_type(8))) short bf16x8;
typedef __attribute__((ext_vector_type(4))) unsigned short u16x4;

__device__ __forceinline__ unsigned short f2bf(float f) {
  uint32_t u = __builtin_bit_cast(uint32_t, f);
  return (unsigned short)((u + 0x7fffu + ((u >> 16) & 1u)) >> 16);
}

__device__ __forceinline__ unsigned short f2h(float f) {
  _Float16 h = (_Float16)f;
  return __builtin_bit_cast(unsigned short, h);
}
__device__ __forceinline__ float h2f(unsigned short u) {
  return (float)__builtin_bit_cast(_Float16, u);
}

__device__ __forceinline__ void gl_lds16(const void* g, void* l) {
  __builtin_amdgcn_global_load_lds(
      (const __attribute__((address_space(1))) void*)g,
      (__attribute__((address_space(3))) void*)l, 16, 0, 0);
}

#define BAR() __builtin_amdgcn_s_barrier()
#define VMC(n) asm volatile("s_waitcnt vmcnt(" #n ")" ::: "memory")

// -------- RoPE cos/sin table: [C][E/2] f32 each --------
__global__ __launch_bounds__(256) void rope_table(float* __restrict__ cosT,
                                                  float* __restrict__ sinT) {
  int idx = blockIdx.x * 256 + threadIdx.x;  // over C*E/2
  int pos = idx >> 9;
  int i = idx & 511;
  double inv = exp(((double)(-2 * i) / 1024.0) * 9.210340371976184);
  double a = (double)pos * inv;
  double r = a - 6.283185307179586 * rint(a * 0.15915494309189535);
  float rf = (float)r;
  float s, c;
  __sincosf(rf, &s, &c);
  cosT[idx] = c;
  sinT[idx] = s;
}

// -------- fused f32 -> bf16 convert for x, Wq, Wk, Wv --------
__global__ __launch_bounds__(256) void cvt_all(const float* __restrict__ x,
                                               const float* __restrict__ wq,
                                               const float* __restrict__ wk,
                                               const float* __restrict__ wv,
                                               unsigned short* __restrict__ x_bf,
                                               unsigned short* __restrict__ w_bf) {
  int b = blockIdx.x;
  const float* in;
  unsigned short* out;
  long off;
  if (b < 16384) { in = x; out = x_bf; off = (long)b * 1024; }
  else if (b < 17408) { in = wq; out = w_bf; off = (long)(b - 16384) * 1024; }
  else if (b < 18432) { in = wk; out = w_bf + (1l << 20); off = (long)(b - 17408) * 1024; }
  else { in = wv; out = w_bf + (2l << 20); off = (long)(b - 18432) * 1024; }
  long i = off + threadIdx.x * 4;
  f32x4 v = *(const f32x4*)(in + i);
  u16x4 o = {f2bf(v.x), f2bf(v.y), f2bf(v.z), f2bf(v.w)};
  *(u16x4*)(out + i) = o;
}

// ======== 256x256 8-phase GEMM, BK=64 — r16 structure (best measured) ========
// 512 threads = 8 waves (2M x 4N). LDS 128 KiB [buf(2)][A/B][half][128][64].
// Top-of-phase ds_reads overlap the barrier wait; tail-reads (bF1/aF2) overlap
// the MFMA drain; compiler emits fine-grained lgkmcnt (no manual pins). Stage
// slots each land after their buffer-half's seal barrier; vmcnt(4) at ph4/ph8
// only. Swizzle: granule ^= row&7 (0 conflicts with 16-row frags),
// inverse-permuted global src + linear gl_lds dest. XCD chunk + 4x4 supertile;
// MODE 2 batch-innermost (mask tile L2 shared).
// MODE 0: fused QKV projection (N=3072=[Q|K|V]); RoPE on Q/K, transpose V.
// MODE 2: *1/32 + mask -> f16 scores; NEW: LDS-bounce epilogue (tile staged in
//         the now-dead 128 KiB LDS with the same g^=row&7 involution, then
//         8-lanes-per-row re-read -> 128B-contiguous stores; 16 VMEM
//         stores/thread instead of 128 scalar 2B stores / 32B segments).
// MODE 3: plain f32 out (PV).
template <int MODE>
__global__ __launch_bounds__(512, 1) void gemm8(
    const unsigned short* __restrict__ A, const unsigned short* __restrict__ Bm,
    long sAb, long sBb, long sOb, int nr, int nc, int K, int N,
    unsigned short* __restrict__ oQ, unsigned short* __restrict__ oK,
    unsigned short* __restrict__ oVt, float* __restrict__ oF,
    const float* __restrict__ cosT, const float* __restrict__ sinT,
    const float* __restrict__ mask) {
  __shared__ unsigned short lds[2][2][2][128 * 64];  // 128 KiB
  const int tid = threadIdx.x;
  const int lane = tid & 63;
  const int wid = tid >> 6;
  const int wm = wid >> 2, wn = wid & 3;  // 2M x 4N
  const int kgrp = lane >> 4, r16 = lane & 15;

  // XCD chunk (nwg%8==0) + 4x4 supertile decode (nr%4==0, nc%4==0)
  const int nwg = gridDim.x;
  const int lid = blockIdx.x;
  const int s = (lid & 7) * (nwg >> 3) + (lid >> 3);
  int bz, rt, ct;
  if (MODE == 2) {
    // batch innermost: 4 consecutive same-XCD blocks share (rt,ct) mask tile
    bz = s & 3;
    const int s4 = s >> 2;
    const int scc = nc >> 2;
    const int sid = s4 >> 4, inner = s4 & 15;
    const int srt = sid / scc, sct = sid - srt * scc;
    rt = srt * 4 + (inner >> 2);
    ct = sct * 4 + (inner & 3);
  } else {
    const int scc = nc >> 2;
    const int per_b_st = (nr >> 2) * scc;
    const int sid = s >> 4, inner = s & 15;
    bz = sid / per_b_st;
    const int r2 = sid - bz * per_b_st;
    const int srt = r2 / scc, sct = r2 - srt * scc;
    rt = srt * 4 + (inner >> 2);
    ct = sct * 4 + (inner & 3);
  }

  const unsigned short* Ag = A + sAb * bz + (long)rt * 256 * K;
  const unsigned short* Bg = Bm + sBb * bz + (long)ct * 256 * K;

  // stage one half-tile (128x64) = 2 gl_lds/thread; LDS linear, src col
  // granule inverse-swizzled by the read involution (g ^= row&7).
  auto stA = [&](int buf, int half, int t) {
#pragma unroll
    for (int q = 0; q < 2; ++q) {
      int G = q * 512 + tid;
      int r = G >> 3, g = G & 7;
      gl_lds16(Ag + (long)(half * 128 + r) * K + t * 64 + ((g ^ (r & 7)) << 3),
               &lds[buf][0][half][G * 8]);
    }
  };
  auto stB = [&](int buf, int half, int t) {
#pragma unroll
    for (int q = 0; q < 2; ++q) {
      int G = q * 512 + tid;
      int r = G >> 3, g = G & 7;
      gl_lds16(Bg + (long)(half * 128 + r) * K + t * 64 + ((g ^ (r & 7)) << 3),
               &lds[buf][1][half][G * 8]);
    }
  };

  f32x4 acc[8][4];
#pragma unroll
  for (int m = 0; m < 8; ++m)
#pragma unroll
    for (int n = 0; n < 4; ++n) acc[m][n] = {0.f, 0.f, 0.f, 0.f};

  bf16x8 aF[8], aF2[8], bF0[4], bF1[4];
  auto rdA = [&](int buf, int mh, bf16x8* d) {
#pragma unroll
    for (int m = 0; m < 4; ++m) {
      int row = mh * 64 + m * 16 + r16;
#pragma unroll
      for (int ks = 0; ks < 2; ++ks)
        d[m * 2 + ks] = *(const bf16x8*)&lds[buf][0][wm]
            [row * 64 + ((((ks << 2) + kgrp) ^ (row & 7)) << 3)];
    }
  };
  auto rdB = [&](int buf, int nh, bf16x8* d) {
#pragma unroll
    for (int n = 0; n < 2; ++n) {
      int row = (wn & 1) * 64 + nh * 32 + n * 16 + r16;
#pragma unroll
      for (int ks = 0; ks < 2; ++ks)
        d[n * 2 + ks] = *(const bf16x8*)&lds[buf][1][wn >> 1]
            [row * 64 + ((((ks << 2) + kgrp) ^ (row & 7)) << 3)];
    }
  };
  auto mm = [&](bf16x8* af, bf16x8* bf, int mh, int nh) {
    __builtin_amdgcn_s_setprio(1);
#pragma unroll
    for (int ks = 0; ks < 2; ++ks)
#pragma unroll
      for (int m = 0; m < 4; ++m)
#pragma unroll
        for (int n = 0; n < 2; ++n)
          acc[mh * 4 + m][nh * 2 + n] = __builtin_amdgcn_mfma_f32_16x16x32_bf16(
              af[m * 2 + ks], bf[n * 2 + ks], acc[mh * 4 + m][nh * 2 + n], 0, 0, 0);
    __builtin_amdgcn_s_setprio(0);
  };

  const int NIT = K >> 7;  // 2 K-tiles (BK=64) per iteration
  stA(0, 0, 0); stA(0, 1, 0); stB(0, 0, 0); stB(0, 1, 0);
  stA(1, 0, 1); stA(1, 1, 1); stB(1, 0, 1); stB(1, 1, 1);
  VMC(8);
  BAR();

  for (int it = 0; it < NIT; ++it) {
    const int t1 = 2 * it + 1, t2 = 2 * it + 2, t3 = 2 * it + 3;
    const bool more = (it + 1 < NIT);
    // ---- ph1: t0 (mh0,nh0); tail-read bF1 for ph2 ----
    rdA(0, 0, aF); rdB(0, 0, bF0);
    if (it > 0) stA(1, 0, t1);
    BAR();
    mm(aF, bF0, 0, 0);
    rdB(0, 1, bF1);        // interleaves with MFMA drain (bF1 unused by ph1)
    BAR();
    // ---- ph2: t0 (mh0,nh1); tail-read aF2 for ph3 ----
    if (it > 0) stA(1, 1, t1);
    BAR();
    mm(aF, bF1, 0, 1);
    rdA(0, 1, aF2);        // interleaves with MFMA drain (aF2 distinct)
    BAR();
    // ---- ph3: t0 (mh1,nh1) ---- buf0-B sealed at ph2 end
    if (more) stB(0, 0, t2);
    BAR();
    mm(aF2, bF1, 1, 1);
    BAR();
    // ---- ph4: t0 (mh1,nh0) ---- vmcnt: tile t1 fully landed for ph5
    if (more) stB(0, 1, t2);
    BAR();
    mm(aF2, bF0, 1, 0);
    if (more) { VMC(4); } else { VMC(0); }
    BAR();
    // ---- ph5: t1 (mh0,nh0); tail-read bF1 ----
    rdA(1, 0, aF); rdB(1, 0, bF0);
    if (more) stA(0, 0, t2);
    BAR();
    mm(aF, bF0, 0, 0);
    rdB(1, 1, bF1);
    BAR();
    // ---- ph6: t1 (mh0,nh1); tail-read aF2 ----
    if (more) stA(0, 1, t2);
    BAR();
    mm(aF, bF1, 0, 1);
    rdA(1, 1, aF2);
    BAR();
    // ---- ph7: t1 (mh1,nh1) ---- buf1-B sealed at ph6 end
    if (more) stB(1, 0, t3);
    BAR();
    mm(aF2, bF1, 1, 1);
    BAR();
    // ---- ph8: t1 (mh1,nh0) ---- vmcnt: tile t2 fully landed for next ph1
    if (more) stB(1, 1, t3);
    BAR();
    mm(aF2, bF0, 1, 0);
    if (more) { VMC(4); BAR(); }
  }

  const int row0 = rt * 256 + wm * 128;
  const int col0 = ct * 256 + wn * 64;

  if (MODE == 2) {
    // ---- LDS-bounce epilogue ----
    // After the final ph8 barrier no wave touches the K-loop LDS; the 128 KiB
    // buffer (= exactly 256x256 u16) is reused as the f16 C-tile. Write side
    // uses the same g ^= row&7 granule involution (2-way max = free); read
    // side assigns 8 lanes per row reading granules lane&7 + 8k -> 8 distinct
    // bank-groups (conflict-free) and 128B-contiguous global segments.
    unsigned short* eps = (unsigned short*)lds;
#pragma unroll
    for (int m = 0; m < 8; ++m) {
#pragma unroll
      for (int n = 0; n < 4; ++n) {
#pragma unroll
        for (int r = 0; r < 4; ++r) {
          int rowL = wm * 128 + m * 16 + kgrp * 4 + r;
          int colL = wn * 64 + n * 16 + r16;
          float sc = acc[m][n][r] * 0.03125f +
                     mask[(long)(rt * 256 + rowL) * C_LEN + ct * 256 + colL];
          int g = colL >> 3, w8 = colL & 7;
          eps[rowL * 256 + ((g ^ (rowL & 7)) << 3) + w8] = f2h(sc);
        }
      }
    }
    __syncthreads();  // drain ds_writes; all tiles staged before any read
    const int lrow8 = wid * 8 + (lane >> 3);  // 0..63
    const int lg = lane & 7;
#pragma unroll
    for (int p = 0; p < 4; ++p) {
      int rowL = p * 64 + lrow8;
      unsigned short* rowp =
          (unsigned short*)(oF + sOb * bz + (long)(rt * 256 + rowL) * C_LEN);
#pragma unroll
      for (int k = 0; k < 4; ++k) {
        int g = lg + k * 8;              // logical granule 0..31
        int phys = g ^ (rowL & 7);
        f32x4 chunk = *(const f32x4*)&eps[rowL * 256 + phys * 8];
        *(f32x4*)&rowp[ct * 256 + g * 8] = chunk;  // 8 lanes -> 128B segment
      }
    }
  } else {
#pragma unroll
    for (int m = 0; m < 8; ++m) {
#pragma unroll
      for (int n = 0; n < 4; ++n) {
#pragma unroll
        for (int r = 0; r < 4; ++r) {
          float v = acc[m][n][r];
          int row = row0 + m * 16 + kgrp * 4 + r;  // C/D: col=lane&15, row=(lane>>4)*4+r
          int col = col0 + n * 16 + r16;
          if (MODE == 0) {
            float pp = __shfl_xor(v, 1);  // RoPE pair partner (col^1, same row/reg)
            int sel = col >> 10;          // 0=Q 1=K 2=V (uniform per 64-col wave slice)
            int lcol = col & 1023;
            if (sel < 2) {
              int pos = row & (C_LEN - 1);
              int i2 = lcol >> 1;
              float c = cosT[pos * (E_DIM / 2) + i2];
              float sn = sinT[pos * (E_DIM / 2) + i2];
              float rv = v * c + ((lcol & 1) ? pp * sn : -pp * sn);
              unsigned short* o = sel ? oK : oQ;
              o[(long)row * E_DIM + lcol] = f2bf(rv);
            } else {
              int b = row >> 12;
              int cc = row & (C_LEN - 1);
              oVt[(long)b * E_DIM * C_LEN + (long)lcol * C_LEN + cc] = f2bf(v);
            }
          } else {
            oF[sOb * bz + (long)row * N + col] = v;
          }
        }
      }
    }
  }
}

// -------- row softmax: read f16 scores (own row's first 8 KB), write f32
// weights in place + bf16 P copy. Row-local: no cross-row hazard. --------
__global__ __launch_bounds__(256) void softmax_rows(float* __restrict__ w,
                                                    unsigned short* __restrict__ pb) {
  long row = blockIdx.x;
  float* p = w + row * C_LEN;
  const unsigned short* ph = (const unsigned short*)p;  // f16 scores
  unsigned short* pbp = pb + row * C_LEN;
  int t = threadIdx.x;
  int wid = t >> 6;
  f32x4 v[4];
  float mx = -3.4e38f;
#pragma unroll
  for (int j = 0; j < 4; ++j) {
    u16x4 hb = *(const u16x4*)(ph + j * 1024 + t * 4);
    v[j].x = h2f(hb.x);
    v[j].y = h2f(hb.y);
    v[j].z = h2f(hb.z);
    v[j].w = h2f(hb.w);
    mx = fmaxf(mx, fmaxf(fmaxf(v[j].x, v[j].y), fmaxf(v[j].z, v[j].w)));
  }
#pragma unroll
  for (int o = 1; o < 64; o <<= 1) mx = fmaxf(mx, __shfl_xor(mx, o));
  __shared__ float redm[4];
  if ((t & 63) == 0) redm[wid] = mx;
  __syncthreads();
  mx = fmaxf(fmaxf(redm[0], redm[1]), fmaxf(redm[2], redm[3]));
  float sum = 0.f;
#pragma unroll
  for (int j = 0; j < 4; ++j) {
    v[j].x = __expf(v[j].x - mx);
    v[j].y = __expf(v[j].y - mx);
    v[j].z = __expf(v[j].z - mx);
    v[j].w = __expf(v[j].w - mx);
    sum += v[j].x + v[j].y + v[j].z + v[j].w;
  }
#pragma unroll
  for (int o = 1; o < 64; o <<= 1) sum += __shfl_xor(sum, o);
  __shared__ float reds[4];
  if ((t & 63) == 0) reds[wid] = sum;
  __syncthreads();
  sum = reds[0] + reds[1] + reds[2] + reds[3];
  float inv = 1.0f / sum;
  __syncthreads();  // all reads of this row's f16 data complete before stores
#pragma unroll
  for (int j = 0; j < 4; ++j) {
    v[j].x *= inv;
    v[j].y *= inv;
    v[j].z *= inv;
    v[j].w *= inv;
    __builtin_nontemporal_store(v[j], (f32x4*)(p + j * 1024 + t * 4));
    u16x4 o16 = {f2bf(v[j].x), f2bf(v[j].y), f2bf(v[j].z), f2bf(v[j].w)};
    *(u16x4*)(pbp + j * 1024 + t * 4) = o16;
  }
}

extern "C" void kernel_launch(void* const* d_in, const int* in_sizes, int n_in,
                              void* d_out, int out_size, void* d_ws, size_t ws_size,
                              hipStream_t stream) {
  const float* x = (const float*)d_in[0];
  const float* mask = (const float*)d_in[1];
  const float* Wq = (const float*)d_in[2];
  const float* Wk = (const float*)d_in[3];
  const float* Wv = (const float*)d_in[4];
  float* out = (float*)d_out;                           // [B][C][E]
  float* weights = out + (long)NBATCH * C_LEN * E_DIM;  // [B][C][C]

  char* ws = (char*)d_ws;
  const bool big = ws_size >= (160ull << 20);
  float* cosT = (float*)(ws);
  float* sinT = (float*)(ws + (8l << 20));
  unsigned short* x_bf = (unsigned short*)(ws + (16l << 20));
  unsigned short* W_bf = (unsigned short*)(ws + (48l << 20));  // [3072][1024] = Q|K|V
  unsigned short* Q_bf = (unsigned short*)(ws + (54l << 20));
  unsigned short* K_bf = (unsigned short*)(ws + (86l << 20));
  unsigned short* Vt = (unsigned short*)(ws + (big ? (128l << 20) : (118l << 20)));
  unsigned short* P_bf = (unsigned short*)(ws);

  dim3 blk(256);
  dim3 blk512(512);

  rope_table<<<dim3((C_LEN * (E_DIM / 2)) / 256), blk, 0, stream>>>(cosT, sinT);
  cvt_all<<<dim3(19456), blk, 0, stream>>>(x, Wq, Wk, Wv, x_bf, W_bf);

  // fused QKV projection: 64 rt x 12 ct = 768 blocks
  gemm8<0><<<dim3(768), blk512, 0, stream>>>(
      x_bf, W_bf, 0, 0, 0, 64, 12, E_DIM, 3 * E_DIM,
      Q_bf, K_bf, Vt, nullptr, cosT, sinT, nullptr);

  // scores = QK^T/32 + mask -> f16 packed into weights rows; 1024 blocks
  gemm8<2><<<dim3(1024), blk512, 0, stream>>>(
      Q_bf, K_bf, (long)C_LEN * E_DIM, (long)C_LEN * E_DIM, (long)C_LEN * C_LEN,
      16, 16, E_DIM, C_LEN, nullptr, nullptr, nullptr, weights, nullptr, nullptr, mask);

  if (big) {
    softmax_rows<<<dim3(NBATCH * C_LEN), blk, 0, stream>>>(weights, P_bf);
    // out = P @ V: 16 rt x 4 ct x 4 bz = 256 blocks
    gemm8<3><<<dim3(256), blk512, 0, stream>>>(
        P_bf, Vt, (long)C_LEN * C_LEN, (long)E_DIM * C_LEN, (long)C_LEN * E_DIM,
        16, 4, C_LEN, E_DIM, nullptr, nullptr, nullptr, out, nullptr, nullptr, nullptr);
  } else {
    for (int h = 0; h < 2; ++h) {
      float* wgt = weights + (long)h * 2 * C_LEN * C_LEN;
      softmax_rows<<<dim3(2 * C_LEN), blk, 0, stream>>>(wgt, P_bf);
      gemm8<3><<<dim3(128), blk512, 0, stream>>>(
          P_bf, Vt + (long)h * 2 * E_DIM * C_LEN, (long)C_LEN * C_LEN, (long)E_DIM * C_LEN,
          (long)C_LEN * E_DIM, 16, 4, C_LEN, E_DIM,
          nullptr, nullptr, nullptr, out + (long)h * 2 * C_LEN * E_DIM,
          nullptr, nullptr, nullptr);
    }
  }
}

// Round 21
// 511.778 us; speedup vs baseline: 1.2297x; 1.1113x over previous
//
#include <hip/hip_runtime.h>
#include <cstdint>

#define C_LEN 4096
#define E_DIM 1024
#define NBATCH 4

typedef __attribute__((ext_vector_type(4))) float f32x4;
typedef __attribute__((ext_vector_type(8))) short bf16x8;
typedef __attribute__((ext_vector_type(4))) unsigned short u16x4;

__device__ __forceinline__ unsigned short f2bf(float f) {
  uint32_t u = __builtin_bit_cast(uint32_t, f);
  return (unsigned short)((u + 0x7fffu + ((u >> 16) & 1u)) >> 16);
}

__device__ __forceinline__ unsigned short f2h(float f) {
  _Float16 h = (_Float16)f;
  return __builtin_bit_cast(unsigned short, h);
}
__device__ __forceinline__ float h2f(unsigned short u) {
  return (float)__builtin_bit_cast(_Float16, u);
}

__device__ __forceinline__ void gl_lds16(const void* g, void* l) {
  __builtin_amdgcn_global_load_lds(
      (const __attribute__((address_space(1))) void*)g,
      (__attribute__((address_space(3))) void*)l, 16, 0, 0);
}

#define BAR() __builtin_amdgcn_s_barrier()
#define VMC(n) asm volatile("s_waitcnt vmcnt(" #n ")" ::: "memory")

// -------- RoPE cos/sin table: [C][E/2] f32 each --------
__global__ __launch_bounds__(256) void rope_table(float* __restrict__ cosT,
                                                  float* __restrict__ sinT) {
  int idx = blockIdx.x * 256 + threadIdx.x;  // over C*E/2
  int pos = idx >> 9;
  int i = idx & 511;
  double inv = exp(((double)(-2 * i) / 1024.0) * 9.210340371976184);
  double a = (double)pos * inv;
  double r = a - 6.283185307179586 * rint(a * 0.15915494309189535);
  float rf = (float)r;
  float s, c;
  __sincosf(rf, &s, &c);
  cosT[idx] = c;
  sinT[idx] = s;
}

// -------- fused f32 -> bf16 convert for x, Wq, Wk, Wv --------
__global__ __launch_bounds__(256) void cvt_all(const float* __restrict__ x,
                                               const float* __restrict__ wq,
                                               const float* __restrict__ wk,
                                               const float* __restrict__ wv,
                                               unsigned short* __restrict__ x_bf,
                                               unsigned short* __restrict__ w_bf) {
  int b = blockIdx.x;
  const float* in;
  unsigned short* out;
  long off;
  if (b < 16384) { in = x; out = x_bf; off = (long)b * 1024; }
  else if (b < 17408) { in = wq; out = w_bf; off = (long)(b - 16384) * 1024; }
  else if (b < 18432) { in = wk; out = w_bf + (1l << 20); off = (long)(b - 17408) * 1024; }
  else { in = wv; out = w_bf + (2l << 20); off = (long)(b - 18432) * 1024; }
  long i = off + threadIdx.x * 4;
  f32x4 v = *(const f32x4*)(in + i);
  u16x4 o = {f2bf(v.x), f2bf(v.y), f2bf(v.z), f2bf(v.w)};
  *(u16x4*)(out + i) = o;
}

// ======== 256x256 8-phase GEMM, BK=64 — r16/r20 structure (best measured) ========
// 512 threads = 8 waves (2M x 4N). LDS 128 KiB [buf(2)][A/B][half][128][64].
// K-loop unchanged from r16. Epilogues:
// MODE 2 (r20-verified) + NEW MODE 0 Q/K tiles: LDS-bounce — tile staged into
// the dead 128 KiB K-loop LDS with granule involution g ^= row&7, then
// 8-lanes-per-row re-read -> 128B-contiguous stores (16 wide stores/thread
// instead of 128 scalar 2B stores at 32B segments). MODE 0 V tiles keep the
// scatter path (transpose). MODE 3 (PV): two-half f32 bounce (each half
// 128x256 f32 = exactly 128 KiB), 64-lane row-contiguous re-read -> 1KB/instr.
// All bounces race-free: every K-loop LDS read precedes the final ph8 barrier.
template <int MODE>
__global__ __launch_bounds__(512, 1) void gemm8(
    const unsigned short* __restrict__ A, const unsigned short* __restrict__ Bm,
    long sAb, long sBb, long sOb, int nr, int nc, int K, int N,
    unsigned short* __restrict__ oQ, unsigned short* __restrict__ oK,
    unsigned short* __restrict__ oVt, float* __restrict__ oF,
    const float* __restrict__ cosT, const float* __restrict__ sinT,
    const float* __restrict__ mask) {
  __shared__ unsigned short lds[2][2][2][128 * 64];  // 128 KiB
  const int tid = threadIdx.x;
  const int lane = tid & 63;
  const int wid = tid >> 6;
  const int wm = wid >> 2, wn = wid & 3;  // 2M x 4N
  const int kgrp = lane >> 4, r16 = lane & 15;

  // XCD chunk (nwg%8==0) + 4x4 supertile decode (nr%4==0, nc%4==0)
  const int nwg = gridDim.x;
  const int lid = blockIdx.x;
  const int s = (lid & 7) * (nwg >> 3) + (lid >> 3);
  int bz, rt, ct;
  if (MODE == 2) {
    // batch innermost: 4 consecutive same-XCD blocks share (rt,ct) mask tile
    bz = s & 3;
    const int s4 = s >> 2;
    const int scc = nc >> 2;
    const int sid = s4 >> 4, inner = s4 & 15;
    const int srt = sid / scc, sct = sid - srt * scc;
    rt = srt * 4 + (inner >> 2);
    ct = sct * 4 + (inner & 3);
  } else {
    const int scc = nc >> 2;
    const int per_b_st = (nr >> 2) * scc;
    const int sid = s >> 4, inner = s & 15;
    bz = sid / per_b_st;
    const int r2 = sid - bz * per_b_st;
    const int srt = r2 / scc, sct = r2 - srt * scc;
    rt = srt * 4 + (inner >> 2);
    ct = sct * 4 + (inner & 3);
  }

  const unsigned short* Ag = A + sAb * bz + (long)rt * 256 * K;
  const unsigned short* Bg = Bm + sBb * bz + (long)ct * 256 * K;

  // stage one half-tile (128x64) = 2 gl_lds/thread; LDS linear, src col
  // granule inverse-swizzled by the read involution (g ^= row&7).
  auto stA = [&](int buf, int half, int t) {
#pragma unroll
    for (int q = 0; q < 2; ++q) {
      int G = q * 512 + tid;
      int r = G >> 3, g = G & 7;
      gl_lds16(Ag + (long)(half * 128 + r) * K + t * 64 + ((g ^ (r & 7)) << 3),
               &lds[buf][0][half][G * 8]);
    }
  };
  auto stB = [&](int buf, int half, int t) {
#pragma unroll
    for (int q = 0; q < 2; ++q) {
      int G = q * 512 + tid;
      int r = G >> 3, g = G & 7;
      gl_lds16(Bg + (long)(half * 128 + r) * K + t * 64 + ((g ^ (r & 7)) << 3),
               &lds[buf][1][half][G * 8]);
    }
  };

  f32x4 acc[8][4];
#pragma unroll
  for (int m = 0; m < 8; ++m)
#pragma unroll
    for (int n = 0; n < 4; ++n) acc[m][n] = {0.f, 0.f, 0.f, 0.f};

  bf16x8 aF[8], aF2[8], bF0[4], bF1[4];
  auto rdA = [&](int buf, int mh, bf16x8* d) {
#pragma unroll
    for (int m = 0; m < 4; ++m) {
      int row = mh * 64 + m * 16 + r16;
#pragma unroll
      for (int ks = 0; ks < 2; ++ks)
        d[m * 2 + ks] = *(const bf16x8*)&lds[buf][0][wm]
            [row * 64 + ((((ks << 2) + kgrp) ^ (row & 7)) << 3)];
    }
  };
  auto rdB = [&](int buf, int nh, bf16x8* d) {
#pragma unroll
    for (int n = 0; n < 2; ++n) {
      int row = (wn & 1) * 64 + nh * 32 + n * 16 + r16;
#pragma unroll
      for (int ks = 0; ks < 2; ++ks)
        d[n * 2 + ks] = *(const bf16x8*)&lds[buf][1][wn >> 1]
            [row * 64 + ((((ks << 2) + kgrp) ^ (row & 7)) << 3)];
    }
  };
  auto mm = [&](bf16x8* af, bf16x8* bf, int mh, int nh) {
    __builtin_amdgcn_s_setprio(1);
#pragma unroll
    for (int ks = 0; ks < 2; ++ks)
#pragma unroll
      for (int m = 0; m < 4; ++m)
#pragma unroll
        for (int n = 0; n < 2; ++n)
          acc[mh * 4 + m][nh * 2 + n] = __builtin_amdgcn_mfma_f32_16x16x32_bf16(
              af[m * 2 + ks], bf[n * 2 + ks], acc[mh * 4 + m][nh * 2 + n], 0, 0, 0);
    __builtin_amdgcn_s_setprio(0);
  };

  const int NIT = K >> 7;  // 2 K-tiles (BK=64) per iteration
  stA(0, 0, 0); stA(0, 1, 0); stB(0, 0, 0); stB(0, 1, 0);
  stA(1, 0, 1); stA(1, 1, 1); stB(1, 0, 1); stB(1, 1, 1);
  VMC(8);
  BAR();

  for (int it = 0; it < NIT; ++it) {
    const int t1 = 2 * it + 1, t2 = 2 * it + 2, t3 = 2 * it + 3;
    const bool more = (it + 1 < NIT);
    // ---- ph1: t0 (mh0,nh0); tail-read bF1 for ph2 ----
    rdA(0, 0, aF); rdB(0, 0, bF0);
    if (it > 0) stA(1, 0, t1);
    BAR();
    mm(aF, bF0, 0, 0);
    rdB(0, 1, bF1);        // interleaves with MFMA drain (bF1 unused by ph1)
    BAR();
    // ---- ph2: t0 (mh0,nh1); tail-read aF2 for ph3 ----
    if (it > 0) stA(1, 1, t1);
    BAR();
    mm(aF, bF1, 0, 1);
    rdA(0, 1, aF2);        // interleaves with MFMA drain (aF2 distinct)
    BAR();
    // ---- ph3: t0 (mh1,nh1) ---- buf0-B sealed at ph2 end
    if (more) stB(0, 0, t2);
    BAR();
    mm(aF2, bF1, 1, 1);
    BAR();
    // ---- ph4: t0 (mh1,nh0) ---- vmcnt: tile t1 fully landed for ph5
    if (more) stB(0, 1, t2);
    BAR();
    mm(aF2, bF0, 1, 0);
    if (more) { VMC(4); } else { VMC(0); }
    BAR();
    // ---- ph5: t1 (mh0,nh0); tail-read bF1 ----
    rdA(1, 0, aF); rdB(1, 0, bF0);
    if (more) stA(0, 0, t2);
    BAR();
    mm(aF, bF0, 0, 0);
    rdB(1, 1, bF1);
    BAR();
    // ---- ph6: t1 (mh0,nh1); tail-read aF2 ----
    if (more) stA(0, 1, t2);
    BAR();
    mm(aF, bF1, 0, 1);
    rdA(1, 1, aF2);
    BAR();
    // ---- ph7: t1 (mh1,nh1) ---- buf1-B sealed at ph6 end
    if (more) stB(1, 0, t3);
    BAR();
    mm(aF2, bF1, 1, 1);
    BAR();
    // ---- ph8: t1 (mh1,nh0) ---- vmcnt: tile t2 fully landed for next ph1
    if (more) stB(1, 1, t3);
    BAR();
    mm(aF2, bF0, 1, 0);
    if (more) { VMC(4); BAR(); }
  }

  const int row0 = rt * 256 + wm * 128;
  const int col0 = ct * 256 + wn * 64;

  if (MODE == 2 || (MODE == 0 && ct < 8)) {
    // ---- u16 LDS-bounce epilogue (scores f16 / proj Q,K bf16+RoPE) ----
    // 128 KiB K-loop LDS (dead after final ph8 barrier) = 256x256 u16 tile.
    // Write with g ^= row&7 involution; read 8 lanes/row -> 128B segments.
    unsigned short* eps = (unsigned short*)lds;
    const int lcol0 = (MODE == 0) ? (ct & 3) * 256 : 0;
#pragma unroll
    for (int m = 0; m < 8; ++m) {
#pragma unroll
      for (int n = 0; n < 4; ++n) {
#pragma unroll
        for (int r = 0; r < 4; ++r) {
          float v = acc[m][n][r];
          int rowL = wm * 128 + m * 16 + kgrp * 4 + r;
          int colL = wn * 64 + n * 16 + r16;
          unsigned short val;
          if (MODE == 2) {
            float sc = v * 0.03125f +
                       mask[(long)(rt * 256 + rowL) * C_LEN + ct * 256 + colL];
            val = f2h(sc);
          } else {
            float pp = __shfl_xor(v, 1);  // RoPE pair (col^1 -> lane^1)
            int lcol = lcol0 + colL;
            int pos = (rt * 256 + rowL) & (C_LEN - 1);
            int i2 = lcol >> 1;
            float c = cosT[pos * (E_DIM / 2) + i2];
            float sn = sinT[pos * (E_DIM / 2) + i2];
            val = f2bf(v * c + ((lcol & 1) ? pp * sn : -pp * sn));
          }
          int g = colL >> 3, w8 = colL & 7;
          eps[rowL * 256 + ((g ^ (rowL & 7)) << 3) + w8] = val;
        }
      }
    }
    __syncthreads();
    const int lrow8 = wid * 8 + (lane >> 3);  // 0..63
    const int lg = lane & 7;
#pragma unroll
    for (int p = 0; p < 4; ++p) {
      int rowL = p * 64 + lrow8;
      unsigned short* rowp;
      if (MODE == 2) {
        rowp = (unsigned short*)(oF + sOb * bz + (long)(rt * 256 + rowL) * C_LEN)
               + ct * 256;
      } else {
        unsigned short* o = (ct < 4) ? oQ : oK;
        rowp = o + (long)(rt * 256 + rowL) * E_DIM + lcol0;
      }
#pragma unroll
      for (int k = 0; k < 4; ++k) {
        int g = lg + k * 8;              // logical granule 0..31
        int phys = g ^ (rowL & 7);
        f32x4 chunk = *(const f32x4*)&eps[rowL * 256 + phys * 8];
        *(f32x4*)&rowp[g * 8] = chunk;   // 8 lanes -> 128B segment
      }
    }
  } else if (MODE == 0) {
    // ---- proj V tile (ct >= 8): transpose scatter (unchanged) ----
#pragma unroll
    for (int m = 0; m < 8; ++m) {
#pragma unroll
      for (int n = 0; n < 4; ++n) {
#pragma unroll
        for (int r = 0; r < 4; ++r) {
          float v = acc[m][n][r];
          int row = row0 + m * 16 + kgrp * 4 + r;
          int col = col0 + n * 16 + r16;
          int lcol = col & 1023;
          int b = row >> 12;
          int cc = row & (C_LEN - 1);
          oVt[(long)b * E_DIM * C_LEN + (long)lcol * C_LEN + cc] = f2bf(v);
        }
      }
    }
  } else {
    // ---- MODE 3 (PV): two-half f32 LDS-bounce ----
    // Half h = rows [h*128, h*128+128) x 256 f32 = exactly 128 KiB. Waves with
    // wm==h own those rows. Involution on low-3 granule bits (16B granules,
    // 64/row): conflict-managed writes, conflict-free 64-lane row reads.
    float* epsf = (float*)lds;
#pragma unroll
    for (int h = 0; h < 2; ++h) {
      if (wm == h) {
#pragma unroll
        for (int m = 0; m < 8; ++m) {
#pragma unroll
          for (int n = 0; n < 4; ++n) {
#pragma unroll
            for (int r = 0; r < 4; ++r) {
              int rowL = m * 16 + kgrp * 4 + r;        // 0..127
              int colL = wn * 64 + n * 16 + r16;       // 0..255
              int g = colL >> 2, w4 = colL & 3;
              int phys = (g & ~7) | ((g & 7) ^ (rowL & 7));
              epsf[rowL * 256 + phys * 4 + w4] = acc[m][n][r];
            }
          }
        }
      }
      __syncthreads();
      // 512 threads: 8 rows/pass x 64 granules; 16 passes. 64 lanes/row ->
      // 1KB contiguous global store per wave-instr.
      const int g = tid & 63;
      const int rsub = tid >> 6;  // 0..7
#pragma unroll
      for (int p = 0; p < 16; ++p) {
        int rowL = p * 8 + rsub;
        int phys = (g & ~7) | ((g & 7) ^ (rowL & 7));
        f32x4 chunk = *(const f32x4*)&epsf[rowL * 256 + phys * 4];
        int grow = rt * 256 + h * 128 + rowL;
        *(f32x4*)&oF[sOb * bz + (long)grow * N + ct * 256 + g * 4] = chunk;
      }
      __syncthreads();  // half-0 reads done before half-1 overwrites
    }
  }
}

// -------- row softmax: read f16 scores (own row's first 8 KB), write f32
// weights in place + bf16 P copy. Row-local: no cross-row hazard. --------
__global__ __launch_bounds__(256) void softmax_rows(float* __restrict__ w,
                                                    unsigned short* __restrict__ pb) {
  long row = blockIdx.x;
  float* p = w + row * C_LEN;
  const unsigned short* ph = (const unsigned short*)p;  // f16 scores
  unsigned short* pbp = pb + row * C_LEN;
  int t = threadIdx.x;
  int wid = t >> 6;
  f32x4 v[4];
  float mx = -3.4e38f;
#pragma unroll
  for (int j = 0; j < 4; ++j) {
    u16x4 hb = *(const u16x4*)(ph + j * 1024 + t * 4);
    v[j].x = h2f(hb.x);
    v[j].y = h2f(hb.y);
    v[j].z = h2f(hb.z);
    v[j].w = h2f(hb.w);
    mx = fmaxf(mx, fmaxf(fmaxf(v[j].x, v[j].y), fmaxf(v[j].z, v[j].w)));
  }
#pragma unroll
  for (int o = 1; o < 64; o <<= 1) mx = fmaxf(mx, __shfl_xor(mx, o));
  __shared__ float redm[4];
  if ((t & 63) == 0) redm[wid] = mx;
  __syncthreads();
  mx = fmaxf(fmaxf(redm[0], redm[1]), fmaxf(redm[2], redm[3]));
  float sum = 0.f;
#pragma unroll
  for (int j = 0; j < 4; ++j) {
    v[j].x = __expf(v[j].x - mx);
    v[j].y = __expf(v[j].y - mx);
    v[j].z = __expf(v[j].z - mx);
    v[j].w = __expf(v[j].w - mx);
    sum += v[j].x + v[j].y + v[j].z + v[j].w;
  }
#pragma unroll
  for (int o = 1; o < 64; o <<= 1) sum += __shfl_xor(sum, o);
  __shared__ float reds[4];
  if ((t & 63) == 0) reds[wid] = sum;
  __syncthreads();
  sum = reds[0] + reds[1] + reds[2] + reds[3];
  float inv = 1.0f / sum;
  __syncthreads();  // all reads of this row's f16 data complete before stores
#pragma unroll
  for (int j = 0; j < 4; ++j) {
    v[j].x *= inv;
    v[j].y *= inv;
    v[j].z *= inv;
    v[j].w *= inv;
    __builtin_nontemporal_store(v[j], (f32x4*)(p + j * 1024 + t * 4));
    u16x4 o16 = {f2bf(v[j].x), f2bf(v[j].y), f2bf(v[j].z), f2bf(v[j].w)};
    *(u16x4*)(pbp + j * 1024 + t * 4) = o16;
  }
}

extern "C" void kernel_launch(void* const* d_in, const int* in_sizes, int n_in,
                              void* d_out, int out_size, void* d_ws, size_t ws_size,
                              hipStream_t stream) {
  const float* x = (const float*)d_in[0];
  const float* mask = (const float*)d_in[1];
  const float* Wq = (const float*)d_in[2];
  const float* Wk = (const float*)d_in[3];
  const float* Wv = (const float*)d_in[4];
  float* out = (float*)d_out;                           // [B][C][E]
  float* weights = out + (long)NBATCH * C_LEN * E_DIM;  // [B][C][C]

  char* ws = (char*)d_ws;
  const bool big = ws_size >= (160ull << 20);
  float* cosT = (float*)(ws);
  float* sinT = (float*)(ws + (8l << 20));
  unsigned short* x_bf = (unsigned short*)(ws + (16l << 20));
  unsigned short* W_bf = (unsigned short*)(ws + (48l << 20));  // [3072][1024] = Q|K|V
  unsigned short* Q_bf = (unsigned short*)(ws + (54l << 20));
  unsigned short* K_bf = (unsigned short*)(ws + (86l << 20));
  unsigned short* Vt = (unsigned short*)(ws + (big ? (128l << 20) : (118l << 20)));
  unsigned short* P_bf = (unsigned short*)(ws);

  dim3 blk(256);
  dim3 blk512(512);

  rope_table<<<dim3((C_LEN * (E_DIM / 2)) / 256), blk, 0, stream>>>(cosT, sinT);
  cvt_all<<<dim3(19456), blk, 0, stream>>>(x, Wq, Wk, Wv, x_bf, W_bf);

  // fused QKV projection: 64 rt x 12 ct = 768 blocks
  gemm8<0><<<dim3(768), blk512, 0, stream>>>(
      x_bf, W_bf, 0, 0, 0, 64, 12, E_DIM, 3 * E_DIM,
      Q_bf, K_bf, Vt, nullptr, cosT, sinT, nullptr);

  // scores = QK^T/32 + mask -> f16 packed into weights rows; 1024 blocks
  gemm8<2><<<dim3(1024), blk512, 0, stream>>>(
      Q_bf, K_bf, (long)C_LEN * E_DIM, (long)C_LEN * E_DIM, (long)C_LEN * C_LEN,
      16, 16, E_DIM, C_LEN, nullptr, nullptr, nullptr, weights, nullptr, nullptr, mask);

  if (big) {
    softmax_rows<<<dim3(NBATCH * C_LEN), blk, 0, stream>>>(weights, P_bf);
    // out = P @ V: 16 rt x 4 ct x 4 bz = 256 blocks
    gemm8<3><<<dim3(256), blk512, 0, stream>>>(
        P_bf, Vt, (long)C_LEN * C_LEN, (long)E_DIM * C_LEN, (long)C_LEN * E_DIM,
        16, 4, C_LEN, E_DIM, nullptr, nullptr, nullptr, out, nullptr, nullptr, nullptr);
  } else {
    for (int h = 0; h < 2; ++h) {
      float* wgt = weights + (long)h * 2 * C_LEN * C_LEN;
      softmax_rows<<<dim3(2 * C_LEN), blk, 0, stream>>>(wgt, P_bf);
      gemm8<3><<<dim3(128), blk512, 0, stream>>>(
          P_bf, Vt + (long)h * 2 * E_DIM * C_LEN, (long)C_LEN * C_LEN, (long)E_DIM * C_LEN,
          (long)C_LEN * E_DIM, 16, 4, C_LEN, E_DIM,
          nullptr, nullptr, nullptr, out + (long)h * 2 * C_LEN * E_DIM,
          nullptr, nullptr, nullptr);
    }
  }
}

// Round 22
// 510.671 us; speedup vs baseline: 1.2324x; 1.0022x over previous
//
#include <hip/hip_runtime.h>
#include <cstdint>

#define C_LEN 4096
#define E_DIM 1024
#define NBATCH 4

typedef __attribute__((ext_vector_type(4))) float f32x4;
typedef __attribute__((ext_vector_type(8))) short bf16x8;
typedef __attribute__((ext_vector_type(4))) unsigned short u16x4;

__device__ __forceinline__ unsigned short f2bf(float f) {
  uint32_t u = __builtin_bit_cast(uint32_t, f);
  return (unsigned short)((u + 0x7fffu + ((u >> 16) & 1u)) >> 16);
}

__device__ __forceinline__ unsigned short f2h(float f) {
  _Float16 h = (_Float16)f;
  return __builtin_bit_cast(unsigned short, h);
}
__device__ __forceinline__ float h2f(unsigned short u) {
  return (float)__builtin_bit_cast(_Float16, u);
}

__device__ __forceinline__ void gl_lds16(const void* g, void* l) {
  __builtin_amdgcn_global_load_lds(
      (const __attribute__((address_space(1))) void*)g,
      (__attribute__((address_space(3))) void*)l, 16, 0, 0);
}

#define BAR() __builtin_amdgcn_s_barrier()
#define VMC(n) asm volatile("s_waitcnt vmcnt(" #n ")" ::: "memory")

// -------- RoPE cos/sin table: [C][E/2] f32 each --------
__global__ __launch_bounds__(256) void rope_table(float* __restrict__ cosT,
                                                  float* __restrict__ sinT) {
  int idx = blockIdx.x * 256 + threadIdx.x;  // over C*E/2
  int pos = idx >> 9;
  int i = idx & 511;
  double inv = exp(((double)(-2 * i) / 1024.0) * 9.210340371976184);
  double a = (double)pos * inv;
  double r = a - 6.283185307179586 * rint(a * 0.15915494309189535);
  float rf = (float)r;
  float s, c;
  __sincosf(rf, &s, &c);
  cosT[idx] = c;
  sinT[idx] = s;
}

// -------- fused f32 -> bf16 convert for x, Wq, Wk, Wv --------
__global__ __launch_bounds__(256) void cvt_all(const float* __restrict__ x,
                                               const float* __restrict__ wq,
                                               const float* __restrict__ wk,
                                               const float* __restrict__ wv,
                                               unsigned short* __restrict__ x_bf,
                                               unsigned short* __restrict__ w_bf) {
  int b = blockIdx.x;
  const float* in;
  unsigned short* out;
  long off;
  if (b < 16384) { in = x; out = x_bf; off = (long)b * 1024; }
  else if (b < 17408) { in = wq; out = w_bf; off = (long)(b - 16384) * 1024; }
  else if (b < 18432) { in = wk; out = w_bf + (1l << 20); off = (long)(b - 17408) * 1024; }
  else { in = wv; out = w_bf + (2l << 20); off = (long)(b - 18432) * 1024; }
  long i = off + threadIdx.x * 4;
  f32x4 v = *(const f32x4*)(in + i);
  u16x4 o = {f2bf(v.x), f2bf(v.y), f2bf(v.z), f2bf(v.w)};
  *(u16x4*)(out + i) = o;
}

// ======== 256x256 8-phase GEMM, BK=64 — r16/r21 structure (best measured) ========
// 512 threads = 8 waves (2M x 4N). LDS 128 KiB [buf(2)][A/B][half][128][64].
// K-loop unchanged from r16. ALL epilogues are now LDS-bounce coalesced:
// MODE 2 scores + MODE 0 Q/K (r20/r21-verified): u16 bounce, g ^= row&7,
//   8 lanes/row -> 128B segments.
// MODE 0 V (NEW): TRANSPOSED u16 bounce — stage eps[colL][rowL] with row-dim
//   granule involution gr ^= colL&7, re-read 8 lanes/colL -> 128B-contiguous
//   stores along cc (replaces 128 scalar 2B stores at stride 8KB/lane).
//   Tile never straddles a batch (4096%256==0) -> b = rt>>4 block-uniform.
// MODE 3 PV (r21-verified): two-half f32 bounce, 1KB/wave-instr stores.
// All bounces race-free: every K-loop LDS read precedes the final ph8 barrier.
template <int MODE>
__global__ __launch_bounds__(512, 1) void gemm8(
    const unsigned short* __restrict__ A, const unsigned short* __restrict__ Bm,
    long sAb, long sBb, long sOb, int nr, int nc, int K, int N,
    unsigned short* __restrict__ oQ, unsigned short* __restrict__ oK,
    unsigned short* __restrict__ oVt, float* __restrict__ oF,
    const float* __restrict__ cosT, const float* __restrict__ sinT,
    const float* __restrict__ mask) {
  __shared__ unsigned short lds[2][2][2][128 * 64];  // 128 KiB
  const int tid = threadIdx.x;
  const int lane = tid & 63;
  const int wid = tid >> 6;
  const int wm = wid >> 2, wn = wid & 3;  // 2M x 4N
  const int kgrp = lane >> 4, r16 = lane & 15;

  // XCD chunk (nwg%8==0) + 4x4 supertile decode (nr%4==0, nc%4==0)
  const int nwg = gridDim.x;
  const int lid = blockIdx.x;
  const int s = (lid & 7) * (nwg >> 3) + (lid >> 3);
  int bz, rt, ct;
  if (MODE == 2) {
    // batch innermost: 4 consecutive same-XCD blocks share (rt,ct) mask tile
    bz = s & 3;
    const int s4 = s >> 2;
    const int scc = nc >> 2;
    const int sid = s4 >> 4, inner = s4 & 15;
    const int srt = sid / scc, sct = sid - srt * scc;
    rt = srt * 4 + (inner >> 2);
    ct = sct * 4 + (inner & 3);
  } else {
    const int scc = nc >> 2;
    const int per_b_st = (nr >> 2) * scc;
    const int sid = s >> 4, inner = s & 15;
    bz = sid / per_b_st;
    const int r2 = sid - bz * per_b_st;
    const int srt = r2 / scc, sct = r2 - srt * scc;
    rt = srt * 4 + (inner >> 2);
    ct = sct * 4 + (inner & 3);
  }

  const unsigned short* Ag = A + sAb * bz + (long)rt * 256 * K;
  const unsigned short* Bg = Bm + sBb * bz + (long)ct * 256 * K;

  // stage one half-tile (128x64) = 2 gl_lds/thread; LDS linear, src col
  // granule inverse-swizzled by the read involution (g ^= row&7).
  auto stA = [&](int buf, int half, int t) {
#pragma unroll
    for (int q = 0; q < 2; ++q) {
      int G = q * 512 + tid;
      int r = G >> 3, g = G & 7;
      gl_lds16(Ag + (long)(half * 128 + r) * K + t * 64 + ((g ^ (r & 7)) << 3),
               &lds[buf][0][half][G * 8]);
    }
  };
  auto stB = [&](int buf, int half, int t) {
#pragma unroll
    for (int q = 0; q < 2; ++q) {
      int G = q * 512 + tid;
      int r = G >> 3, g = G & 7;
      gl_lds16(Bg + (long)(half * 128 + r) * K + t * 64 + ((g ^ (r & 7)) << 3),
               &lds[buf][1][half][G * 8]);
    }
  };

  f32x4 acc[8][4];
#pragma unroll
  for (int m = 0; m < 8; ++m)
#pragma unroll
    for (int n = 0; n < 4; ++n) acc[m][n] = {0.f, 0.f, 0.f, 0.f};

  bf16x8 aF[8], aF2[8], bF0[4], bF1[4];
  auto rdA = [&](int buf, int mh, bf16x8* d) {
#pragma unroll
    for (int m = 0; m < 4; ++m) {
      int row = mh * 64 + m * 16 + r16;
#pragma unroll
      for (int ks = 0; ks < 2; ++ks)
        d[m * 2 + ks] = *(const bf16x8*)&lds[buf][0][wm]
            [row * 64 + ((((ks << 2) + kgrp) ^ (row & 7)) << 3)];
    }
  };
  auto rdB = [&](int buf, int nh, bf16x8* d) {
#pragma unroll
    for (int n = 0; n < 2; ++n) {
      int row = (wn & 1) * 64 + nh * 32 + n * 16 + r16;
#pragma unroll
      for (int ks = 0; ks < 2; ++ks)
        d[n * 2 + ks] = *(const bf16x8*)&lds[buf][1][wn >> 1]
            [row * 64 + ((((ks << 2) + kgrp) ^ (row & 7)) << 3)];
    }
  };
  auto mm = [&](bf16x8* af, bf16x8* bf, int mh, int nh) {
    __builtin_amdgcn_s_setprio(1);
#pragma unroll
    for (int ks = 0; ks < 2; ++ks)
#pragma unroll
      for (int m = 0; m < 4; ++m)
#pragma unroll
        for (int n = 0; n < 2; ++n)
          acc[mh * 4 + m][nh * 2 + n] = __builtin_amdgcn_mfma_f32_16x16x32_bf16(
              af[m * 2 + ks], bf[n * 2 + ks], acc[mh * 4 + m][nh * 2 + n], 0, 0, 0);
    __builtin_amdgcn_s_setprio(0);
  };

  const int NIT = K >> 7;  // 2 K-tiles (BK=64) per iteration
  stA(0, 0, 0); stA(0, 1, 0); stB(0, 0, 0); stB(0, 1, 0);
  stA(1, 0, 1); stA(1, 1, 1); stB(1, 0, 1); stB(1, 1, 1);
  VMC(8);
  BAR();

  for (int it = 0; it < NIT; ++it) {
    const int t1 = 2 * it + 1, t2 = 2 * it + 2, t3 = 2 * it + 3;
    const bool more = (it + 1 < NIT);
    // ---- ph1: t0 (mh0,nh0); tail-read bF1 for ph2 ----
    rdA(0, 0, aF); rdB(0, 0, bF0);
    if (it > 0) stA(1, 0, t1);
    BAR();
    mm(aF, bF0, 0, 0);
    rdB(0, 1, bF1);        // interleaves with MFMA drain (bF1 unused by ph1)
    BAR();
    // ---- ph2: t0 (mh0,nh1); tail-read aF2 for ph3 ----
    if (it > 0) stA(1, 1, t1);
    BAR();
    mm(aF, bF1, 0, 1);
    rdA(0, 1, aF2);        // interleaves with MFMA drain (aF2 distinct)
    BAR();
    // ---- ph3: t0 (mh1,nh1) ---- buf0-B sealed at ph2 end
    if (more) stB(0, 0, t2);
    BAR();
    mm(aF2, bF1, 1, 1);
    BAR();
    // ---- ph4: t0 (mh1,nh0) ---- vmcnt: tile t1 fully landed for ph5
    if (more) stB(0, 1, t2);
    BAR();
    mm(aF2, bF0, 1, 0);
    if (more) { VMC(4); } else { VMC(0); }
    BAR();
    // ---- ph5: t1 (mh0,nh0); tail-read bF1 ----
    rdA(1, 0, aF); rdB(1, 0, bF0);
    if (more) stA(0, 0, t2);
    BAR();
    mm(aF, bF0, 0, 0);
    rdB(1, 1, bF1);
    BAR();
    // ---- ph6: t1 (mh0,nh1); tail-read aF2 ----
    if (more) stA(0, 1, t2);
    BAR();
    mm(aF, bF1, 0, 1);
    rdA(1, 1, aF2);
    BAR();
    // ---- ph7: t1 (mh1,nh1) ---- buf1-B sealed at ph6 end
    if (more) stB(1, 0, t3);
    BAR();
    mm(aF2, bF1, 1, 1);
    BAR();
    // ---- ph8: t1 (mh1,nh0) ---- vmcnt: tile t2 fully landed for next ph1
    if (more) stB(1, 1, t3);
    BAR();
    mm(aF2, bF0, 1, 0);
    if (more) { VMC(4); BAR(); }
  }

  if (MODE == 2 || (MODE == 0 && ct < 8)) {
    // ---- u16 LDS-bounce epilogue (scores f16 / proj Q,K bf16+RoPE) ----
    unsigned short* eps = (unsigned short*)lds;
    const int lcol0 = (MODE == 0) ? (ct & 3) * 256 : 0;
#pragma unroll
    for (int m = 0; m < 8; ++m) {
#pragma unroll
      for (int n = 0; n < 4; ++n) {
#pragma unroll
        for (int r = 0; r < 4; ++r) {
          float v = acc[m][n][r];
          int rowL = wm * 128 + m * 16 + kgrp * 4 + r;
          int colL = wn * 64 + n * 16 + r16;
          unsigned short val;
          if (MODE == 2) {
            float sc = v * 0.03125f +
                       mask[(long)(rt * 256 + rowL) * C_LEN + ct * 256 + colL];
            val = f2h(sc);
          } else {
            float pp = __shfl_xor(v, 1);  // RoPE pair (col^1 -> lane^1)
            int lcol = lcol0 + colL;
            int pos = (rt * 256 + rowL) & (C_LEN - 1);
            int i2 = lcol >> 1;
            float c = cosT[pos * (E_DIM / 2) + i2];
            float sn = sinT[pos * (E_DIM / 2) + i2];
            val = f2bf(v * c + ((lcol & 1) ? pp * sn : -pp * sn));
          }
          int g = colL >> 3, w8 = colL & 7;
          eps[rowL * 256 + ((g ^ (rowL & 7)) << 3) + w8] = val;
        }
      }
    }
    __syncthreads();
    const int lrow8 = wid * 8 + (lane >> 3);  // 0..63
    const int lg = lane & 7;
#pragma unroll
    for (int p = 0; p < 4; ++p) {
      int rowL = p * 64 + lrow8;
      unsigned short* rowp;
      if (MODE == 2) {
        rowp = (unsigned short*)(oF + sOb * bz + (long)(rt * 256 + rowL) * C_LEN)
               + ct * 256;
      } else {
        unsigned short* o = (ct < 4) ? oQ : oK;
        rowp = o + (long)(rt * 256 + rowL) * E_DIM + lcol0;
      }
#pragma unroll
      for (int k = 0; k < 4; ++k) {
        int g = lg + k * 8;              // logical granule 0..31
        int phys = g ^ (rowL & 7);
        f32x4 chunk = *(const f32x4*)&eps[rowL * 256 + phys * 8];
        *(f32x4*)&rowp[g * 8] = chunk;   // 8 lanes -> 128B segment
      }
    }
  } else if (MODE == 0) {
    // ---- proj V tile (ct >= 8): TRANSPOSED u16 bounce ----
    // Stage eps[colL][rowL] with row-dim granule involution gr ^= colL&7;
    // re-read 8 lanes/colL -> 128B-contiguous stores along cc.
    unsigned short* eps = (unsigned short*)lds;
#pragma unroll
    for (int m = 0; m < 8; ++m) {
#pragma unroll
      for (int n = 0; n < 4; ++n) {
#pragma unroll
        for (int r = 0; r < 4; ++r) {
          int rowL = wm * 128 + m * 16 + kgrp * 4 + r;
          int colL = wn * 64 + n * 16 + r16;
          int gr = rowL >> 3, w8 = rowL & 7;
          eps[colL * 256 + ((gr ^ (colL & 7)) << 3) + w8] = f2bf(acc[m][n][r]);
        }
      }
    }
    __syncthreads();
    const int lrow8 = wid * 8 + (lane >> 3);  // 0..63
    const int lg = lane & 7;
    const int b = rt >> 4;                    // 4096/256=16 tiles/batch
    const int cc0 = (rt & 15) * 256;
    const int lcolbase = (ct - 8) * 256;
#pragma unroll
    for (int p = 0; p < 4; ++p) {
      int colL = p * 64 + lrow8;
      unsigned short* colp = oVt + (long)b * E_DIM * C_LEN +
                             (long)(lcolbase + colL) * C_LEN + cc0;
#pragma unroll
      for (int k = 0; k < 4; ++k) {
        int g = lg + k * 8;              // logical row-granule 0..31
        int phys = g ^ (colL & 7);
        f32x4 chunk = *(const f32x4*)&eps[colL * 256 + phys * 8];
        *(f32x4*)&colp[g * 8] = chunk;   // 8 lanes -> 128B segment along cc
      }
    }
  } else {
    // ---- MODE 3 (PV): two-half f32 LDS-bounce (r21-verified) ----
    float* epsf = (float*)lds;
#pragma unroll
    for (int h = 0; h < 2; ++h) {
      if (wm == h) {
#pragma unroll
        for (int m = 0; m < 8; ++m) {
#pragma unroll
          for (int n = 0; n < 4; ++n) {
#pragma unroll
            for (int r = 0; r < 4; ++r) {
              int rowL = m * 16 + kgrp * 4 + r;        // 0..127
              int colL = wn * 64 + n * 16 + r16;       // 0..255
              int g = colL >> 2, w4 = colL & 3;
              int phys = (g & ~7) | ((g & 7) ^ (rowL & 7));
              epsf[rowL * 256 + phys * 4 + w4] = acc[m][n][r];
            }
          }
        }
      }
      __syncthreads();
      const int g = tid & 63;
      const int rsub = tid >> 6;  // 0..7
#pragma unroll
      for (int p = 0; p < 16; ++p) {
        int rowL = p * 8 + rsub;
        int phys = (g & ~7) | ((g & 7) ^ (rowL & 7));
        f32x4 chunk = *(const f32x4*)&epsf[rowL * 256 + phys * 4];
        int grow = rt * 256 + h * 128 + rowL;
        *(f32x4*)&oF[sOb * bz + (long)grow * N + ct * 256 + g * 4] = chunk;
      }
      __syncthreads();  // half-0 reads done before half-1 overwrites
    }
  }
}

// -------- row softmax: read f16 scores (own row's first 8 KB), write f32
// weights in place + bf16 P copy. Row-local: no cross-row hazard. --------
__global__ __launch_bounds__(256) void softmax_rows(float* __restrict__ w,
                                                    unsigned short* __restrict__ pb) {
  long row = blockIdx.x;
  float* p = w + row * C_LEN;
  const unsigned short* ph = (const unsigned short*)p;  // f16 scores
  unsigned short* pbp = pb + row * C_LEN;
  int t = threadIdx.x;
  int wid = t >> 6;
  f32x4 v[4];
  float mx = -3.4e38f;
#pragma unroll
  for (int j = 0; j < 4; ++j) {
    u16x4 hb = *(const u16x4*)(ph + j * 1024 + t * 4);
    v[j].x = h2f(hb.x);
    v[j].y = h2f(hb.y);
    v[j].z = h2f(hb.z);
    v[j].w = h2f(hb.w);
    mx = fmaxf(mx, fmaxf(fmaxf(v[j].x, v[j].y), fmaxf(v[j].z, v[j].w)));
  }
#pragma unroll
  for (int o = 1; o < 64; o <<= 1) mx = fmaxf(mx, __shfl_xor(mx, o));
  __shared__ float redm[4];
  if ((t & 63) == 0) redm[wid] = mx;
  __syncthreads();
  mx = fmaxf(fmaxf(redm[0], redm[1]), fmaxf(redm[2], redm[3]));
  float sum = 0.f;
#pragma unroll
  for (int j = 0; j < 4; ++j) {
    v[j].x = __expf(v[j].x - mx);
    v[j].y = __expf(v[j].y - mx);
    v[j].z = __expf(v[j].z - mx);
    v[j].w = __expf(v[j].w - mx);
    sum += v[j].x + v[j].y + v[j].z + v[j].w;
  }
#pragma unroll
  for (int o = 1; o < 64; o <<= 1) sum += __shfl_xor(sum, o);
  __shared__ float reds[4];
  if ((t & 63) == 0) reds[wid] = sum;
  __syncthreads();
  sum = reds[0] + reds[1] + reds[2] + reds[3];
  float inv = 1.0f / sum;
  __syncthreads();  // all reads of this row's f16 data complete before stores
#pragma unroll
  for (int j = 0; j < 4; ++j) {
    v[j].x *= inv;
    v[j].y *= inv;
    v[j].z *= inv;
    v[j].w *= inv;
    __builtin_nontemporal_store(v[j], (f32x4*)(p + j * 1024 + t * 4));
    u16x4 o16 = {f2bf(v[j].x), f2bf(v[j].y), f2bf(v[j].z), f2bf(v[j].w)};
    *(u16x4*)(pbp + j * 1024 + t * 4) = o16;
  }
}

extern "C" void kernel_launch(void* const* d_in, const int* in_sizes, int n_in,
                              void* d_out, int out_size, void* d_ws, size_t ws_size,
                              hipStream_t stream) {
  const float* x = (const float*)d_in[0];
  const float* mask = (const float*)d_in[1];
  const float* Wq = (const float*)d_in[2];
  const float* Wk = (const float*)d_in[3];
  const float* Wv = (const float*)d_in[4];
  float* out = (float*)d_out;                           // [B][C][E]
  float* weights = out + (long)NBATCH * C_LEN * E_DIM;  // [B][C][C]

  char* ws = (char*)d_ws;
  const bool big = ws_size >= (160ull << 20);
  float* cosT = (float*)(ws);
  float* sinT = (float*)(ws + (8l << 20));
  unsigned short* x_bf = (unsigned short*)(ws + (16l << 20));
  unsigned short* W_bf = (unsigned short*)(ws + (48l << 20));  // [3072][1024] = Q|K|V
  unsigned short* Q_bf = (unsigned short*)(ws + (54l << 20));
  unsigned short* K_bf = (unsigned short*)(ws + (86l << 20));
  unsigned short* Vt = (unsigned short*)(ws + (big ? (128l << 20) : (118l << 20)));
  unsigned short* P_bf = (unsigned short*)(ws);

  dim3 blk(256);
  dim3 blk512(512);

  rope_table<<<dim3((C_LEN * (E_DIM / 2)) / 256), blk, 0, stream>>>(cosT, sinT);
  cvt_all<<<dim3(19456), blk, 0, stream>>>(x, Wq, Wk, Wv, x_bf, W_bf);

  // fused QKV projection: 64 rt x 12 ct = 768 blocks
  gemm8<0><<<dim3(768), blk512, 0, stream>>>(
      x_bf, W_bf, 0, 0, 0, 64, 12, E_DIM, 3 * E_DIM,
      Q_bf, K_bf, Vt, nullptr, cosT, sinT, nullptr);

  // scores = QK^T/32 + mask -> f16 packed into weights rows; 1024 blocks
  gemm8<2><<<dim3(1024), blk512, 0, stream>>>(
      Q_bf, K_bf, (long)C_LEN * E_DIM, (long)C_LEN * E_DIM, (long)C_LEN * C_LEN,
      16, 16, E_DIM, C_LEN, nullptr, nullptr, nullptr, weights, nullptr, nullptr, mask);

  if (big) {
    softmax_rows<<<dim3(NBATCH * C_LEN), blk, 0, stream>>>(weights, P_bf);
    // out = P @ V: 16 rt x 4 ct x 4 bz = 256 blocks
    gemm8<3><<<dim3(256), blk512, 0, stream>>>(
        P_bf, Vt, (long)C_LEN * C_LEN, (long)E_DIM * C_LEN, (long)C_LEN * E_DIM,
        16, 4, C_LEN, E_DIM, nullptr, nullptr, nullptr, out, nullptr, nullptr, nullptr);
  } else {
    for (int h = 0; h < 2; ++h) {
      float* wgt = weights + (long)h * 2 * C_LEN * C_LEN;
      softmax_rows<<<dim3(2 * C_LEN), blk, 0, stream>>>(wgt, P_bf);
      gemm8<3><<<dim3(128), blk512, 0, stream>>>(
          P_bf, Vt + (long)h * 2 * E_DIM * C_LEN, (long)C_LEN * C_LEN, (long)E_DIM * C_LEN,
          (long)C_LEN * E_DIM, 16, 4, C_LEN, E_DIM,
          nullptr, nullptr, nullptr, out + (long)h * 2 * C_LEN * E_DIM,
          nullptr, nullptr, nullptr);
    }
  }
}